// Round 2
// baseline (596.512 us; speedup 1.0000x reference)
//
#include <hip/hip_runtime.h>
#include <hip/hip_bf16.h>

#define N_NODES 10000
#define NE 160000
#define E2 (NE + N_NODES)   // 170000 edges incl. self loops
#define SQRT_C 0.1f
#define CC 0.01f
#define EPS 1e-15f
#define MAXNORM ((1.0f - 4e-3f) / SQRT_C)   // geoopt projx boundary, 9.96

// dual-dtype load: harness may hand float arrays as bf16 or float32; a sniffer
// kernel votes once and every load branches (wave-uniform) on the flag.
__device__ __forceinline__ float ldf(const void* p, int i, int isbf) {
    return isbf ? __bfloat162float(((const __hip_bfloat16*)p)[i])
                : ((const float*)p)[i];
}

// ---------- wave-wide helpers (wave64) ----------
__device__ __forceinline__ float wsum(float v) {
#pragma unroll
    for (int off = 32; off > 0; off >>= 1) v += __shfl_xor(v, off, 64);
    return v;
}
__device__ __forceinline__ float dev_expmap0(float u) {
    float n = fmaxf(sqrtf(wsum(u * u)), EPS);
    return tanhf(SQRT_C * n) * u / (SQRT_C * n);
}
__device__ __forceinline__ float dev_projx(float x) {
    float n = fmaxf(sqrtf(wsum(x * x)), EPS);
    return (n > MAXNORM) ? x / n * MAXNORM : x;
}
__device__ __forceinline__ float dev_logmap0(float x) {
    float n = fmaxf(sqrtf(wsum(x * x)), EPS);
    float t = fminf(SQRT_C * n, 1.0f - 1e-7f);   // n >= 0 so lower clip is moot
    return atanhf(t) * x / (SQRT_C * n);
}

// monotone float -> uint mapping for atomicMax on floats
__device__ __forceinline__ unsigned fkey(float f) {
    unsigned b = __float_as_uint(f);
    unsigned m = (b & 0x80000000u) ? 0xFFFFFFFFu : 0x80000000u;
    return b ^ m;
}
__device__ __forceinline__ float fkey_dec(unsigned k) {
    unsigned b = (k & 0x80000000u) ? (k ^ 0x80000000u) : ~k;
    return __uint_as_float(b);
}

// ---------- kernel 0: zero accumulators + sniff float dtype ----------
// dtype vote: if emb is bf16, word t's low half is a bf16 of N(0,1) -> exponent
// byte in [116,133] with p~0.999; if emb is float32, the low half is uniform
// mantissa bits -> p~0.07. 64-word majority vote is ~40 sigma separated.
__global__ __launch_bounds__(256) void init_zero_sniff(unsigned* __restrict__ p,
                                                       const unsigned* __restrict__ embw,
                                                       int* __restrict__ flag) {
    int t = blockIdx.x * 256 + threadIdx.x;   // grid sized exactly: 480000 words
    p[t] = 0u;
    if (blockIdx.x == 0 && threadIdx.x < 64) {   // one full wave
        unsigned w = embw[threadIdx.x];
        unsigned e = (w >> 7) & 0xFFu;           // exponent of low-half bf16
        unsigned long long m = __ballot(e >= 116u && e <= 133u);
        if (threadIdx.x == 0) *flag = (__popcll(m) >= 32) ? 1 : 0;
    }
}

// ---------- kernel 1: per-node tangent features + attention dot products ----------
__global__ __launch_bounds__(256) void node_pre(const void* __restrict__ emb,
                                                const void* __restrict__ att_i,
                                                const void* __restrict__ att_j,
                                                const int* __restrict__ flag,
                                                float* __restrict__ xt,
                                                float* __restrict__ ai,
                                                float* __restrict__ aj) {
    int isbf = *flag;
    int t = blockIdx.x * 256 + threadIdx.x;   // grid exact: 10000*64 threads
    int node = t >> 6;
    int lane = t & 63;
    float u = ldf(emb, node * 64 + lane, isbf);
    float x0 = dev_projx(dev_expmap0(u));
    float xv = dev_logmap0(x0);
    xt[node * 64 + lane] = xv;
    float pi = xv * ldf(att_i, lane, isbf);
    float pj = xv * ldf(att_j, lane, isbf);
#pragma unroll
    for (int off = 8; off > 0; off >>= 1) {   // reduce within aligned 16-lane head groups
        pi += __shfl_xor(pi, off, 64);
        pj += __shfl_xor(pj, off, 64);
    }
    if ((lane & 15) == 0) {
        ai[node * 4 + (lane >> 4)] = pi;
        aj[node * 4 + (lane >> 4)] = pj;
    }
}

// only graphs 3 (b=0) and 7 (b=1) reach the output (last timestep slice)
#define EDGE_PREAMBLE()                                                   \
    int t = blockIdx.x * 256 + threadIdx.x;                               \
    if (t >= 2 * E2) return;                                              \
    int slot = (t >= E2) ? 1 : 0;                                         \
    int e = t - slot * E2;                                                \
    int g = slot ? 7 : 3;                                                 \
    int src, dst;                                                         \
    if (e < NE) { src = ei[g * 2 * NE + e]; dst = ei[g * 2 * NE + NE + e]; } \
    else { src = e - NE; dst = src; }

// ---------- kernel 2: segment max of leaky-relu logits ----------
__global__ __launch_bounds__(256) void edge_max(const int* __restrict__ ei,
                                                const float* __restrict__ ai,
                                                const float* __restrict__ aj,
                                                unsigned* __restrict__ mkey) {
    EDGE_PREAMBLE();
    const float* aip = ai + src * 4;
    const float* ajp = aj + dst * 4;
    unsigned* mp = mkey + (slot * N_NODES + src) * 4;
#pragma unroll
    for (int h = 0; h < 4; ++h) {
        float al = aip[h] + ajp[h];
        al = (al < 0.0f) ? 0.2f * al : al;
        atomicMax(mp + h, fkey(al));
    }
}

// ---------- kernel 3: segment sum of exp(alpha - m) ----------
__global__ __launch_bounds__(256) void edge_sum(const int* __restrict__ ei,
                                                const float* __restrict__ ai,
                                                const float* __restrict__ aj,
                                                const unsigned* __restrict__ mkey,
                                                float* __restrict__ ssum) {
    EDGE_PREAMBLE();
    const float* aip = ai + src * 4;
    const float* ajp = aj + dst * 4;
    const unsigned* mp = mkey + (slot * N_NODES + src) * 4;
    float* sp = ssum + (slot * N_NODES + src) * 4;
#pragma unroll
    for (int h = 0; h < 4; ++h) {
        float al = aip[h] + ajp[h];
        al = (al < 0.0f) ? 0.2f * al : al;
        atomicAdd(sp + h, expf(al - fkey_dec(mp[h])));
    }
}

// ---------- kernel 4: normalized weighted aggregation (head-mean folded in) ----------
__global__ __launch_bounds__(256) void edge_agg(const int* __restrict__ ei,
                                                const float* __restrict__ ai,
                                                const float* __restrict__ aj,
                                                const unsigned* __restrict__ mkey,
                                                const float* __restrict__ ssum,
                                                const float* __restrict__ xt,
                                                float* __restrict__ sup) {
    EDGE_PREAMBLE();
    const float* aip = ai + src * 4;
    const float* ajp = aj + dst * 4;
    const unsigned* mp = mkey + (slot * N_NODES + src) * 4;
    const float* sp = ssum + (slot * N_NODES + src) * 4;
    float wgt[4];
#pragma unroll
    for (int h = 0; h < 4; ++h) {
        float al = aip[h] + ajp[h];
        al = (al < 0.0f) ? 0.2f * al : al;
        wgt[h] = 0.25f * expf(al - fkey_dec(mp[h])) / (sp[h] + 1e-16f);
    }
    const float4* xj = (const float4*)(xt + dst * 64);
    float val[16];
#pragma unroll
    for (int c = 0; c < 16; ++c) val[c] = 0.0f;
#pragma unroll
    for (int h = 0; h < 4; ++h) {
#pragma unroll
        for (int q = 0; q < 4; ++q) {
            float4 x4 = xj[h * 4 + q];
            val[q * 4 + 0] = fmaf(wgt[h], x4.x, val[q * 4 + 0]);
            val[q * 4 + 1] = fmaf(wgt[h], x4.y, val[q * 4 + 1]);
            val[q * 4 + 2] = fmaf(wgt[h], x4.z, val[q * 4 + 2]);
            val[q * 4 + 3] = fmaf(wgt[h], x4.w, val[q * 4 + 3]);
        }
    }
    float* supp = sup + (slot * N_NODES + src) * 16;
#pragma unroll
    for (int c = 0; c < 16; ++c) atomicAdd(supp + c, val[c]);
}

// ---------- kernel 5: hyperbolic head (wave per node) ----------
template <int K>
__device__ __forceinline__ float dev_hyp_linear(float xlane, const float* xvec,
                                                const float* wt, const float* hb, int lane) {
    float xn = fmaxf(sqrtf(wsum(xlane * xlane)), EPS);
    float mx = 0.0f;
#pragma unroll
    for (int c = 0; c < K; ++c) mx = fmaf(wt[c * 64 + lane], xvec[c], mx);
    float mxn = fmaxf(sqrtf(wsum(mx * mx)), EPS);
    float t = fminf(SQRT_C * xn, 1.0f - 1e-7f);
    float res = tanhf(mxn / xn * atanhf(t)) * mx / (mxn * SQRT_C);
    if (__ballot(mx != 0.0f) == 0ull) res = 0.0f;   // jnp.all(mx==0) guard
    res = dev_projx(res);
    float y = hb[lane];                              // mobius_add(res, hb)
    float x2 = wsum(res * res);
    float y2 = wsum(y * y);
    float xy = wsum(res * y);
    float num = (1.0f + 2.0f * CC * xy + CC * y2) * res + (1.0f - CC * x2) * y;
    float den = 1.0f + 2.0f * CC * xy + CC * CC * x2 * y2;
    float z = num / fmaxf(den, EPS);
    return dev_projx(z);
}

__global__ __launch_bounds__(256) void final_stage(const float* __restrict__ sup,
                                                   const void* __restrict__ w1g,
                                                   const void* __restrict__ b1g,
                                                   const void* __restrict__ w2g,
                                                   const void* __restrict__ b2g,
                                                   const int* __restrict__ flag,
                                                   void* __restrict__ outv) {
    __shared__ float w1t[16 * 64];   // transposed [c][o]: lane-contiguous, conflict-free
    __shared__ float w2t[64 * 64];
    __shared__ float hb1[64], hb2[64];
    __shared__ float xs[4][16];
    __shared__ float zs[4][64];
    int isbf = *flag;
    int tid = threadIdx.x;
    for (int i = tid; i < 1024; i += 256) {
        int o = i >> 4, c = i & 15;
        w1t[c * 64 + o] = ldf(w1g, i, isbf);
    }
    for (int i = tid; i < 4096; i += 256) {
        int o = i >> 6, c = i & 63;
        w2t[c * 64 + o] = ldf(w2g, i, isbf);
    }
    int w = tid >> 6, lane = tid & 63;
    if (w == 0) hb1[lane] = dev_projx(dev_expmap0(ldf(b1g, lane, isbf)));
    if (w == 1) hb2[lane] = dev_projx(dev_expmap0(ldf(b2g, lane, isbf)));

    int idx = blockIdx.x * 4 + w;            // grid exact: 20000 waves
    int slot = (idx >= N_NODES) ? 1 : 0;     // slot == batch index b
    int n = idx - slot * N_NODES;

    float v = (lane < 16) ? sup[(slot * N_NODES + n) * 16 + lane] : 0.0f;
    float x0 = dev_projx(dev_expmap0(v));    // h = projx(expmap0(sup_mean))
    if (lane < 16) xs[w][lane] = x0;
    __syncthreads();

    float z1 = dev_hyp_linear<16>(x0, xs[w], w1t, hb1, lane);   // 16 -> 64
    float u = dev_logmap0(z1);                                  // HypAct(SiLU)
    u = u / (1.0f + expf(-u));
    float z2 = dev_projx(dev_expmap0(u));
    float u2 = dev_logmap0(z2);                                 // HypDropout eval round-trip
    float z3 = dev_projx(dev_expmap0(u2));
    zs[w][lane] = z3;
    __syncthreads();

    float z4 = dev_hyp_linear<64>(z3, zs[w], w2t, hb2, lane);   // 64 -> 64
    int oidx = (slot * N_NODES + n) * 64 + lane;
    if (isbf) ((__hip_bfloat16*)outv)[oidx] = __float2bfloat16(z4);
    else      ((float*)outv)[oidx] = z4;
}

extern "C" void kernel_launch(void* const* d_in, const int* in_sizes, int n_in,
                              void* d_out, int out_size, void* d_ws, size_t ws_size,
                              hipStream_t stream) {
    // setup_inputs order: history_graphs(0, unused), edge_index(1), emb(2),
    //                     att_i(3), att_j(4), w1(5), b1(6), w2(7), b2(8)
    const int* ei = (const int*)d_in[1];
    const void* emb   = d_in[2];
    const void* att_i = d_in[3];
    const void* att_j = d_in[4];
    const void* w1 = d_in[5];
    const void* b1 = d_in[6];
    const void* w2 = d_in[7];
    const void* b2 = d_in[8];

    // workspace layout (floats): ~4.8 MB total
    float* ws = (float*)d_ws;
    float* xt = ws;                                 // [10000][64]
    float* ai = ws + 640000;                        // [10000][4]
    float* aj = ws + 680000;                        // [10000][4]
    unsigned* mkey = (unsigned*)(ws + 720000);      // [2][10000][4]
    float* ssum = ws + 800000;                      // [2][10000][4]
    float* sup  = ws + 880000;                      // [2][10000][16]
    int* flag   = (int*)(ws + 1200000);             // dtype flag

    hipLaunchKernelGGL(init_zero_sniff, dim3(1875), dim3(256), 0, stream,
                       (unsigned*)(ws + 720000), (const unsigned*)emb, flag);  // 480000 words
    hipLaunchKernelGGL(node_pre, dim3(2500), dim3(256), 0, stream,
                       emb, att_i, att_j, flag, xt, ai, aj);
    int eb = (2 * E2 + 255) / 256;
    hipLaunchKernelGGL(edge_max, dim3(eb), dim3(256), 0, stream, ei, ai, aj, mkey);
    hipLaunchKernelGGL(edge_sum, dim3(eb), dim3(256), 0, stream, ei, ai, aj, mkey, ssum);
    hipLaunchKernelGGL(edge_agg, dim3(eb), dim3(256), 0, stream, ei, ai, aj, mkey, ssum, xt, sup);
    hipLaunchKernelGGL(final_stage, dim3(5000), dim3(256), 0, stream,
                       sup, w1, b1, w2, b2, flag, d_out);
}

// Round 3
// 297.876 us; speedup vs baseline: 2.0026x; 2.0026x over previous
//
#include <hip/hip_runtime.h>
#include <hip/hip_bf16.h>

#define N_NODES 10000
#define NE 160000
#define SQRT_C 0.1f
#define CC 0.01f
#define EPS 1e-15f
#define MAXNORM ((1.0f - 4e-3f) / SQRT_C)   // geoopt projx boundary, 9.96

// dual-dtype load: harness may hand float arrays as bf16 or float32; a sniffer
// kernel votes once and every load branches (wave-uniform) on the flag.
__device__ __forceinline__ float ldf(const void* p, int i, int isbf) {
    return isbf ? __bfloat162float(((const __hip_bfloat16*)p)[i])
                : ((const float*)p)[i];
}

// ---------- wave-wide helpers (wave64) ----------
__device__ __forceinline__ float wsum(float v) {
#pragma unroll
    for (int off = 32; off > 0; off >>= 1) v += __shfl_xor(v, off, 64);
    return v;
}
__device__ __forceinline__ float dev_expmap0(float u) {
    float n = fmaxf(sqrtf(wsum(u * u)), EPS);
    return tanhf(SQRT_C * n) * u / (SQRT_C * n);
}
__device__ __forceinline__ float dev_projx(float x) {
    float n = fmaxf(sqrtf(wsum(x * x)), EPS);
    return (n > MAXNORM) ? x / n * MAXNORM : x;
}
__device__ __forceinline__ float dev_logmap0(float x) {
    float n = fmaxf(sqrtf(wsum(x * x)), EPS);
    float t = fminf(SQRT_C * n, 1.0f - 1e-7f);
    return atanhf(t) * x / (SQRT_C * n);
}

// ---------- kernel 0: zero per-node counters + sniff float dtype ----------
// bf16 data -> low half of a 32b word is a bf16 of N(0,1): exponent in [116,133]
// with p~0.999; f32 data -> low half is uniform mantissa bits: p~0.07.
__global__ __launch_bounds__(256) void init_sniff(int* __restrict__ cnt,
                                                  const unsigned* __restrict__ embw,
                                                  int* __restrict__ flag) {
    int t = blockIdx.x * 256 + threadIdx.x;
    if (t < 2 * N_NODES) cnt[t] = 0;
    if (blockIdx.x == 0 && threadIdx.x < 64) {   // one full wave
        unsigned w = embw[threadIdx.x];
        unsigned e = (w >> 7) & 0xFFu;
        unsigned long long m = __ballot(e >= 116u && e <= 133u);
        if (threadIdx.x == 0) *flag = (__popcll(m) >= 32) ? 1 : 0;
    }
}

// ---------- kernel 1: per-node tangent features + attention dot products ----------
__global__ __launch_bounds__(256) void node_pre(const void* __restrict__ emb,
                                                const void* __restrict__ att_i,
                                                const void* __restrict__ att_j,
                                                const int* __restrict__ flag,
                                                float* __restrict__ xt,
                                                float* __restrict__ ai,
                                                float* __restrict__ aj) {
    int isbf = *flag;
    int t = blockIdx.x * 256 + threadIdx.x;   // grid exact: 10000*64 threads
    int node = t >> 6;
    int lane = t & 63;
    float u = ldf(emb, node * 64 + lane, isbf);
    float x0 = dev_projx(dev_expmap0(u));
    float xv = dev_logmap0(x0);
    xt[node * 64 + lane] = xv;
    float pi = xv * ldf(att_i, lane, isbf);
    float pj = xv * ldf(att_j, lane, isbf);
#pragma unroll
    for (int off = 8; off > 0; off >>= 1) {   // reduce within aligned 16-lane head groups
        pi += __shfl_xor(pi, off, 64);
        pj += __shfl_xor(pj, off, 64);
    }
    if ((lane & 15) == 0) {
        ai[node * 4 + (lane >> 4)] = pi;
        aj[node * 4 + (lane >> 4)] = pj;
    }
}

// only graphs 3 (b=0) and 7 (b=1) reach the output (last-timestep slice).
// real edges only (self loops folded analytically into node_agg).
#define EDGE_PREAMBLE()                                                   \
    int t = blockIdx.x * 256 + threadIdx.x;   /* grid exact: 2*NE */      \
    int slot = (t >= NE) ? 1 : 0;                                         \
    int e = t - slot * NE;                                                \
    int g = slot ? 7 : 3;

// ---------- kernel 2: per-(slot,src) edge counts ----------
__global__ __launch_bounds__(256) void edge_count(const int* __restrict__ ei,
                                                  int* __restrict__ cnt) {
    EDGE_PREAMBLE();
    int src = ei[g * 2 * NE + e];
    atomicAdd(&cnt[slot * N_NODES + src], 1);
}

// ---------- kernel 3: exclusive prefix scan over 20000 counts (1 block) ----------
__global__ __launch_bounds__(1024) void scan_offsets(const int* __restrict__ cnt,
                                                     int* __restrict__ off,
                                                     int* __restrict__ cur) {
    __shared__ int wtot[16];
    const int TOT = 2 * N_NODES;
    const int CH = 20;                     // 1024*20 = 20480 >= 20000
    int t = threadIdx.x;
    int lane = t & 63, w = t >> 6;
    int base = t * CH;
    int s = 0;
#pragma unroll
    for (int i = 0; i < CH; ++i) {
        int idx = base + i;
        s += (idx < TOT) ? cnt[idx] : 0;
    }
    int inc = s;                           // inclusive scan within wave
    for (int o = 1; o < 64; o <<= 1) {
        int v = __shfl_up(inc, o, 64);
        if (lane >= o) inc += v;
    }
    if (lane == 63) wtot[w] = inc;
    __syncthreads();
    if (w == 0 && lane < 16) {
        int v = wtot[lane];
        int iv = v;
        for (int o = 1; o < 16; o <<= 1) {
            int u2 = __shfl_up(iv, o, 64);
            if (lane >= o) iv += u2;
        }
        wtot[lane] = iv - v;               // exclusive wave prefix
    }
    __syncthreads();
    int run = inc - s + wtot[w];           // exclusive prefix for this chunk
#pragma unroll
    for (int i = 0; i < CH; ++i) {
        int idx = base + i;
        if (idx < TOT) {
            off[idx] = run;
            cur[idx] = run;
            run += cnt[idx];
        }
    }
}

// ---------- kernel 4: scatter dst ids into src-grouped buckets ----------
__global__ __launch_bounds__(256) void edge_scatter(const int* __restrict__ ei,
                                                    int* __restrict__ cur,
                                                    unsigned short* __restrict__ bucket) {
    EDGE_PREAMBLE();
    int src = ei[g * 2 * NE + e];
    int dst = ei[g * 2 * NE + NE + e];
    int pos = atomicAdd(&cur[slot * N_NODES + src], 1);
    bucket[pos] = (unsigned short)dst;
}

// ---------- kernel 5: per-node softmax + aggregation, atomic-free ----------
// one wave per (slot,node). After scatter, cur[i] == off[i] + count[i].
__global__ __launch_bounds__(256) void node_agg(const int* __restrict__ off,
                                                const int* __restrict__ cur,
                                                const unsigned short* __restrict__ bucket,
                                                const float* __restrict__ ai,
                                                const float* __restrict__ aj,
                                                const float* __restrict__ xt,
                                                float* __restrict__ sup) {
    int w = threadIdx.x >> 6, lane = threadIdx.x & 63;
    int idx = blockIdx.x * 4 + w;          // grid exact: 20000 waves
    int n = (idx >= N_NODES) ? idx - N_NODES : idx;
    int start = off[idx], end = cur[idx];

    float ain[4], ajn[4];
#pragma unroll
    for (int h = 0; h < 4; ++h) { ain[h] = ai[n * 4 + h]; ajn[h] = aj[n * 4 + h]; }

    // phase A: per-head max (self-loop included in every lane; max is idempotent)
    float mh[4];
#pragma unroll
    for (int h = 0; h < 4; ++h) {
        float a = ain[h] + ajn[h];
        mh[h] = (a < 0.0f) ? 0.2f * a : a;
    }
    for (int e = start + lane; e < end; e += 64) {
        int d = bucket[e];
#pragma unroll
        for (int h = 0; h < 4; ++h) {
            float a = ain[h] + aj[d * 4 + h];
            a = (a < 0.0f) ? 0.2f * a : a;
            mh[h] = fmaxf(mh[h], a);
        }
    }
#pragma unroll
    for (int h = 0; h < 4; ++h)
#pragma unroll
        for (int o = 32; o > 0; o >>= 1) mh[h] = fmaxf(mh[h], __shfl_xor(mh[h], o, 64));

    // phase B: per-head sum of exp(alpha - m) (self-loop counted once, lane 0)
    float sh[4] = {0.f, 0.f, 0.f, 0.f};
    if (lane == 0) {
#pragma unroll
        for (int h = 0; h < 4; ++h) {
            float a = ain[h] + ajn[h];
            a = (a < 0.0f) ? 0.2f * a : a;
            sh[h] = expf(a - mh[h]);
        }
    }
    for (int e = start + lane; e < end; e += 64) {
        int d = bucket[e];
#pragma unroll
        for (int h = 0; h < 4; ++h) {
            float a = ain[h] + aj[d * 4 + h];
            a = (a < 0.0f) ? 0.2f * a : a;
            sh[h] += expf(a - mh[h]);
        }
    }
#pragma unroll
    for (int h = 0; h < 4; ++h) sh[h] = wsum(sh[h]);
    float scale[4];
#pragma unroll
    for (int h = 0; h < 4; ++h) scale[h] = 0.25f / (sh[h] + 1e-16f);

    // phase C: whole-wave weighted gather; lane = h*16 + c
    int hh = lane >> 4;
    float aih = ain[hh], mhh = mh[hh], sch = scale[hh];
    float aself = aih + ajn[hh];
    aself = (aself < 0.0f) ? 0.2f * aself : aself;
    float acc = expf(aself - mhh) * sch * xt[n * 64 + lane];
    for (int e = start; e < end; ++e) {
        int d = bucket[e];                 // wave-uniform scalar
        float a = aih + aj[d * 4 + hh];
        a = (a < 0.0f) ? 0.2f * a : a;
        acc = fmaf(expf(a - mhh) * sch, xt[d * 64 + lane], acc);
    }
    acc += __shfl_xor(acc, 16, 64);        // head mean (x0.25 folded into scale)
    acc += __shfl_xor(acc, 32, 64);
    if (lane < 16) sup[idx * 16 + lane] = acc;
}

// ---------- kernel 6: hyperbolic head (wave per node, shfl-broadcast vectors) ----------
template <int K>
__device__ __forceinline__ float hyp_linear_w(float xlane, const float* wt,
                                              const float* hb, int lane) {
    float xn = fmaxf(sqrtf(wsum(xlane * xlane)), EPS);
    float mx = 0.0f;
#pragma unroll
    for (int c = 0; c < K; ++c) mx = fmaf(wt[c * 64 + lane], __shfl(xlane, c, 64), mx);
    float mxn = fmaxf(sqrtf(wsum(mx * mx)), EPS);
    float t = fminf(SQRT_C * xn, 1.0f - 1e-7f);
    float res = tanhf(mxn / xn * atanhf(t)) * mx / (mxn * SQRT_C);
    if (__ballot(mx != 0.0f) == 0ull) res = 0.0f;   // jnp.all(mx==0) guard
    res = dev_projx(res);
    float y = hb[lane];                              // mobius_add(res, hb)
    float x2 = wsum(res * res);
    float y2 = wsum(y * y);
    float xy = wsum(res * y);
    float num = (1.0f + 2.0f * CC * xy + CC * y2) * res + (1.0f - CC * x2) * y;
    float den = 1.0f + 2.0f * CC * xy + CC * CC * x2 * y2;
    float z = num / fmaxf(den, EPS);
    return dev_projx(z);
}

__global__ __launch_bounds__(256) void final_stage(const float* __restrict__ sup,
                                                   const void* __restrict__ w1g,
                                                   const void* __restrict__ b1g,
                                                   const void* __restrict__ w2g,
                                                   const void* __restrict__ b2g,
                                                   const int* __restrict__ flag,
                                                   void* __restrict__ outv) {
    __shared__ float w1t[16 * 64];   // transposed [c][o]: wave-uniform row reads
    __shared__ float w2t[64 * 64];
    __shared__ float hb1[64], hb2[64];
    int isbf = *flag;
    int tid = threadIdx.x;
    for (int i = tid; i < 1024; i += 256) {
        int o = i >> 4, c = i & 15;
        w1t[c * 64 + o] = ldf(w1g, i, isbf);
    }
    for (int i = tid; i < 4096; i += 256) {
        int o = i >> 6, c = i & 63;
        w2t[c * 64 + o] = ldf(w2g, i, isbf);
    }
    int w = tid >> 6, lane = tid & 63;
    if (w == 0) hb1[lane] = dev_projx(dev_expmap0(ldf(b1g, lane, isbf)));
    if (w == 1) hb2[lane] = dev_projx(dev_expmap0(ldf(b2g, lane, isbf)));
    __syncthreads();

#pragma unroll 1
    for (int r = 0; r < 4; ++r) {          // 4 nodes per wave; grid exact: 1250 blocks
        int idx = (blockIdx.x * 4 + w) * 4 + r;   // [0, 20000)

        float v = (lane < 16) ? sup[idx * 16 + lane] : 0.0f;
        float x0 = dev_projx(dev_expmap0(v));     // h = projx(expmap0(sup_mean))

        float z1 = hyp_linear_w<16>(x0, w1t, hb1, lane);   // 16 -> 64
        float u = dev_logmap0(z1);                          // HypAct(SiLU)
        u = u / (1.0f + expf(-u));
        float z2 = dev_projx(dev_expmap0(u));
        float u2 = dev_logmap0(z2);                         // HypDropout eval round-trip
        float z3 = dev_projx(dev_expmap0(u2));

        float z4 = hyp_linear_w<64>(z3, w2t, hb2, lane);    // 64 -> 64
        int oidx = idx * 64 + lane;
        if (isbf) ((__hip_bfloat16*)outv)[oidx] = __float2bfloat16(z4);
        else      ((float*)outv)[oidx] = z4;
    }
}

extern "C" void kernel_launch(void* const* d_in, const int* in_sizes, int n_in,
                              void* d_out, int out_size, void* d_ws, size_t ws_size,
                              hipStream_t stream) {
    // setup_inputs order: history_graphs(0, unused), edge_index(1), emb(2),
    //                     att_i(3), att_j(4), w1(5), b1(6), w2(7), b2(8)
    const int* ei = (const int*)d_in[1];
    const void* emb   = d_in[2];
    const void* att_i = d_in[3];
    const void* att_j = d_in[4];
    const void* w1 = d_in[5];
    const void* b1 = d_in[6];
    const void* w2 = d_in[7];
    const void* b2 = d_in[8];

    // workspace layout (float words), ~5.05 MB total
    float* ws = (float*)d_ws;
    float* xt  = ws;                                  // [10000][64]
    float* ai  = ws + 640000;                         // [10000][4]
    float* aj  = ws + 680000;                         // [10000][4]
    float* sup = ws + 720000;                         // [2][10000][16]
    int* cnt   = (int*)(ws + 1040000);                // [2][10000]
    int* off   = (int*)(ws + 1060000);                // [2][10000]
    int* cur   = (int*)(ws + 1080000);                // [2][10000]
    unsigned short* bucket = (unsigned short*)(ws + 1100000);  // [320000] u16
    int* flag  = (int*)(ws + 1260000);                // dtype flag

    hipLaunchKernelGGL(init_sniff, dim3(79), dim3(256), 0, stream,
                       cnt, (const unsigned*)emb, flag);
    hipLaunchKernelGGL(node_pre, dim3(2500), dim3(256), 0, stream,
                       emb, att_i, att_j, flag, xt, ai, aj);
    hipLaunchKernelGGL(edge_count, dim3(1250), dim3(256), 0, stream, ei, cnt);
    hipLaunchKernelGGL(scan_offsets, dim3(1), dim3(1024), 0, stream, cnt, off, cur);
    hipLaunchKernelGGL(edge_scatter, dim3(1250), dim3(256), 0, stream, ei, cur, bucket);
    hipLaunchKernelGGL(node_agg, dim3(5000), dim3(256), 0, stream,
                       off, cur, bucket, ai, aj, xt, sup);
    hipLaunchKernelGGL(final_stage, dim3(1250), dim3(256), 0, stream,
                       sup, w1, b1, w2, b2, flag, d_out);
}

// Round 4
// 265.749 us; speedup vs baseline: 2.2446x; 1.1209x over previous
//
#include <hip/hip_runtime.h>
#include <hip/hip_bf16.h>

#define N_NODES 10000
#define NE 160000
#define SQRT_C 0.1f
#define CC 0.01f
#define EPS 1e-15f
#define MAXNORM ((1.0f - 4e-3f) / SQRT_C)   // geoopt projx boundary, 9.96

// dual-dtype load: harness may hand float arrays as bf16 or float32; a sniffer
// kernel votes once and every load branches (wave-uniform) on the flag.
__device__ __forceinline__ float ldf(const void* p, int i, int isbf) {
    return isbf ? __bfloat162float(((const __hip_bfloat16*)p)[i])
                : ((const float*)p)[i];
}

// ---------- wave-wide helpers (wave64) ----------
__device__ __forceinline__ float wsum(float v) {
#pragma unroll
    for (int off = 32; off > 0; off >>= 1) v += __shfl_xor(v, off, 64);
    return v;
}

// ---------- kernel 0: zero per-node counters + sniff float dtype ----------
__global__ __launch_bounds__(256) void init_sniff(int* __restrict__ cnt,
                                                  const unsigned* __restrict__ embw,
                                                  int* __restrict__ flag) {
    int t = blockIdx.x * 256 + threadIdx.x;
    if (t < 2 * N_NODES) cnt[t] = 0;
    if (blockIdx.x == 0 && threadIdx.x < 64) {   // one full wave
        unsigned w = embw[threadIdx.x];
        unsigned e = (w >> 7) & 0xFFu;           // exponent of low-half bf16
        unsigned long long m = __ballot(e >= 116u && e <= 133u);
        if (threadIdx.x == 0) *flag = (__popcll(m) >= 32) ? 1 : 0;
    }
}

// only graphs 3 (b=0) and 7 (b=1) reach the output (last-timestep slice)
#define EDGE_PREAMBLE(T)                                                  \
    int slot = ((T) >= NE) ? 1 : 0;                                       \
    int e = (T) - slot * NE;                                              \
    int g = slot ? 7 : 3;

// ---------- kernel 1: fused node features + edge counting ----------
// blocks [0,2500): wave-per-node tangent features + attention dots (analytic norms)
// blocks [2500,3750): per-(slot,src) edge counts
__global__ __launch_bounds__(256) void pre_count(const void* __restrict__ emb,
                                                 const void* __restrict__ att_i,
                                                 const void* __restrict__ att_j,
                                                 const int* __restrict__ flag,
                                                 const int* __restrict__ ei,
                                                 float* __restrict__ xt,
                                                 float* __restrict__ ai,
                                                 float* __restrict__ aj,
                                                 int* __restrict__ cnt) {
    if (blockIdx.x < 2500) {
        int isbf = *flag;
        int t = blockIdx.x * 256 + threadIdx.x;   // 10000*64 threads exact
        int node = t >> 6;
        int lane = t & 63;
        float u = ldf(emb, node * 64 + lane, isbf);
        // xt = logmap0(projx(expmap0(u))): one wsum, then analytic norms
        float n = fmaxf(sqrtf(wsum(u * u)), EPS);
        float th = tanhf(SQRT_C * n);
        float x0 = th / (SQRT_C * n) * u;
        float x0n = th / SQRT_C;
        if (x0n > MAXNORM) { x0 *= MAXNORM / x0n; x0n = MAXNORM; }
        float tc = fminf(SQRT_C * x0n, 1.0f - 1e-7f);
        float xv = atanhf(tc) / (SQRT_C * x0n) * x0;
        xt[node * 64 + lane] = xv;
        float pi = xv * ldf(att_i, lane, isbf);
        float pj = xv * ldf(att_j, lane, isbf);
#pragma unroll
        for (int off = 8; off > 0; off >>= 1) {   // aligned 16-lane head groups
            pi += __shfl_xor(pi, off, 64);
            pj += __shfl_xor(pj, off, 64);
        }
        if ((lane & 15) == 0) {
            ai[node * 4 + (lane >> 4)] = pi;
            aj[node * 4 + (lane >> 4)] = pj;
        }
    } else {
        int t = (blockIdx.x - 2500) * 256 + threadIdx.x;   // 2*NE exact
        EDGE_PREAMBLE(t);
        int src = ei[g * 2 * NE + e];
        atomicAdd(&cnt[slot * N_NODES + src], 1);
    }
}

// ---------- kernel 2: exclusive prefix scan over 20000 counts (1 block) ----------
__global__ __launch_bounds__(1024) void scan_offsets(const int* __restrict__ cnt,
                                                     int* __restrict__ off,
                                                     int* __restrict__ cur) {
    __shared__ int wtot[16];
    const int TOT = 2 * N_NODES;
    const int CH = 20;                     // 1024*20 >= 20000
    int t = threadIdx.x;
    int lane = t & 63, w = t >> 6;
    int base = t * CH;
    int s = 0;
#pragma unroll
    for (int i = 0; i < CH; ++i) {
        int idx = base + i;
        s += (idx < TOT) ? cnt[idx] : 0;
    }
    int inc = s;
    for (int o = 1; o < 64; o <<= 1) {
        int v = __shfl_up(inc, o, 64);
        if (lane >= o) inc += v;
    }
    if (lane == 63) wtot[w] = inc;
    __syncthreads();
    if (w == 0 && lane < 16) {
        int v = wtot[lane];
        int iv = v;
        for (int o = 1; o < 16; o <<= 1) {
            int u2 = __shfl_up(iv, o, 64);
            if (lane >= o) iv += u2;
        }
        wtot[lane] = iv - v;
    }
    __syncthreads();
    int run = inc - s + wtot[w];
#pragma unroll
    for (int i = 0; i < CH; ++i) {
        int idx = base + i;
        if (idx < TOT) {
            off[idx] = run;
            cur[idx] = run;
            run += cnt[idx];
        }
    }
}

// ---------- kernel 3: scatter dst ids into src-grouped buckets ----------
__global__ __launch_bounds__(256) void edge_scatter(const int* __restrict__ ei,
                                                    int* __restrict__ cur,
                                                    unsigned short* __restrict__ bucket) {
    int t = blockIdx.x * 256 + threadIdx.x;   // 2*NE exact
    EDGE_PREAMBLE(t);
    int src = ei[g * 2 * NE + e];
    int dst = ei[g * 2 * NE + NE + e];
    int pos = atomicAdd(&cur[slot * N_NODES + src], 1);
    bucket[pos] = (unsigned short)dst;
}

// ---------- kernel 4: per-node softmax + aggregation, atomic-free ----------
__global__ __launch_bounds__(256) void node_agg(const int* __restrict__ off,
                                                const int* __restrict__ cur,
                                                const unsigned short* __restrict__ bucket,
                                                const float* __restrict__ ai,
                                                const float* __restrict__ aj,
                                                const float* __restrict__ xt,
                                                float* __restrict__ sup) {
    int w = threadIdx.x >> 6, lane = threadIdx.x & 63;
    int idx = blockIdx.x * 4 + w;          // grid exact: 20000 waves
    int n = (idx >= N_NODES) ? idx - N_NODES : idx;
    int start = off[idx], end = cur[idx];

    float ain[4], ajn[4];
#pragma unroll
    for (int h = 0; h < 4; ++h) { ain[h] = ai[n * 4 + h]; ajn[h] = aj[n * 4 + h]; }

    // phase A: per-head max (self-loop in every lane; max is idempotent)
    float mh[4];
#pragma unroll
    for (int h = 0; h < 4; ++h) {
        float a = ain[h] + ajn[h];
        mh[h] = (a < 0.0f) ? 0.2f * a : a;
    }
    for (int e = start + lane; e < end; e += 64) {
        int d = bucket[e];
#pragma unroll
        for (int h = 0; h < 4; ++h) {
            float a = ain[h] + aj[d * 4 + h];
            a = (a < 0.0f) ? 0.2f * a : a;
            mh[h] = fmaxf(mh[h], a);
        }
    }
#pragma unroll
    for (int h = 0; h < 4; ++h)
#pragma unroll
        for (int o = 32; o > 0; o >>= 1) mh[h] = fmaxf(mh[h], __shfl_xor(mh[h], o, 64));

    // phase B: per-head sum of exp(alpha - m) (self-loop once, lane 0)
    float sh[4] = {0.f, 0.f, 0.f, 0.f};
    if (lane == 0) {
#pragma unroll
        for (int h = 0; h < 4; ++h) {
            float a = ain[h] + ajn[h];
            a = (a < 0.0f) ? 0.2f * a : a;
            sh[h] = expf(a - mh[h]);
        }
    }
    for (int e = start + lane; e < end; e += 64) {
        int d = bucket[e];
#pragma unroll
        for (int h = 0; h < 4; ++h) {
            float a = ain[h] + aj[d * 4 + h];
            a = (a < 0.0f) ? 0.2f * a : a;
            sh[h] += expf(a - mh[h]);
        }
    }
#pragma unroll
    for (int h = 0; h < 4; ++h) sh[h] = wsum(sh[h]);
    float scale[4];
#pragma unroll
    for (int h = 0; h < 4; ++h) scale[h] = 0.25f / (sh[h] + 1e-16f);

    // phase C: whole-wave weighted gather; lane = h*16 + c
    int hh = lane >> 4;
    float aih = ain[hh], mhh = mh[hh], sch = scale[hh];
    float aself = aih + ajn[hh];
    aself = (aself < 0.0f) ? 0.2f * aself : aself;
    float acc = expf(aself - mhh) * sch * xt[n * 64 + lane];
    for (int e = start; e < end; ++e) {
        int d = bucket[e];                 // wave-uniform scalar
        float a = aih + aj[d * 4 + hh];
        a = (a < 0.0f) ? 0.2f * a : a;
        acc = fmaf(expf(a - mhh) * sch, xt[d * 64 + lane], acc);
    }
    acc += __shfl_xor(acc, 16, 64);        // head mean (x0.25 in scale)
    acc += __shfl_xor(acc, 32, 64);
    if (lane < 16) sup[idx * 16 + lane] = acc;
}

// ---------- kernel 5: hyperbolic head, norm-tracked ----------
// hyp_linear with known input norm xn; returns value and sets *out_n.
// LDS stride S padded: S=68 (K=16) banks 4c+lane, S=65 (K=64) banks c+lane -> 2-way, free.
template <int K, int S>
__device__ __forceinline__ float hyp_linear_n(float x, float xn, const float* wt,
                                              const float* hb, float hbn2, int lane,
                                              float* out_n) {
    xn = fmaxf(xn, EPS);
    float m0 = 0.f, m1 = 0.f, m2 = 0.f, m3 = 0.f;   // 4-way ILP on the fma chain
#pragma unroll
    for (int c = 0; c < K; c += 4) {
        m0 = fmaf(wt[(c + 0) * S + lane], __shfl(x, c + 0, 64), m0);
        m1 = fmaf(wt[(c + 1) * S + lane], __shfl(x, c + 1, 64), m1);
        m2 = fmaf(wt[(c + 2) * S + lane], __shfl(x, c + 2, 64), m2);
        m3 = fmaf(wt[(c + 3) * S + lane], __shfl(x, c + 3, 64), m3);
    }
    float mx = (m0 + m1) + (m2 + m3);
    float mxn = fmaxf(sqrtf(wsum(mx * mx)), EPS);
    float t = fminf(SQRT_C * xn, 1.0f - 1e-7f);
    float th = tanhf(mxn / xn * atanhf(t));
    float res = th * mx / (mxn * SQRT_C);
    float rn = th / SQRT_C;                          // analytic norm (th >= 0)
    if (__ballot(mx != 0.0f) == 0ull) { res = 0.0f; rn = 0.0f; }  // all(mx==0) guard
    if (rn > MAXNORM) { res *= MAXNORM / rn; rn = MAXNORM; }      // projx analytic
    float y = hb[lane];                              // mobius_add(res, hb)
    float x2 = rn * rn;
    float xy = wsum(res * y);
    float num = (1.0f + 2.0f * CC * xy + CC * hbn2) * res + (1.0f - CC * x2) * y;
    float den = 1.0f + 2.0f * CC * xy + CC * CC * x2 * hbn2;
    float z = num / fmaxf(den, EPS);
    float zn = fmaxf(sqrtf(wsum(z * z)), EPS);
    if (zn > MAXNORM) { z *= MAXNORM / zn; zn = MAXNORM; }
    *out_n = zn;
    return z;
}

__global__ __launch_bounds__(256) void final_stage(const float* __restrict__ sup,
                                                   const void* __restrict__ w1g,
                                                   const void* __restrict__ b1g,
                                                   const void* __restrict__ w2g,
                                                   const void* __restrict__ b2g,
                                                   const int* __restrict__ flag,
                                                   void* __restrict__ outv) {
    __shared__ float w1t[16 * 68];
    __shared__ float w2t[64 * 65];
    __shared__ float hb1[64], hb2[64];
    __shared__ float hbn2s[2];
    int isbf = *flag;
    int tid = threadIdx.x;
    for (int i = tid; i < 1024; i += 256) {          // w1 [o][c] -> w1t[c*68+o]
        int o = i >> 4, c = i & 15;
        w1t[c * 68 + o] = ldf(w1g, i, isbf);
    }
    for (int i = tid; i < 4096; i += 256) {          // w2 [o][c] -> w2t[c*65+o]
        int o = i >> 6, c = i & 63;
        w2t[c * 65 + o] = ldf(w2g, i, isbf);
    }
    int w = tid >> 6, lane = tid & 63;
    if (w < 2) {                                     // hb = projx(expmap0(b)), + norm^2
        const void* bg = w ? b2g : b1g;
        float b = ldf(bg, lane, isbf);
        float n = fmaxf(sqrtf(wsum(b * b)), EPS);
        float th = tanhf(SQRT_C * n);
        float hv = th / (SQRT_C * n) * b;
        float hn = th / SQRT_C;
        if (hn > MAXNORM) { hv *= MAXNORM / hn; hn = MAXNORM; }
        (w ? hb2 : hb1)[lane] = hv;
        if (lane == 0) hbn2s[w] = hn * hn;
    }
    __syncthreads();
    float h1n2 = hbn2s[0], h2n2 = hbn2s[1];

#pragma unroll 1
    for (int r = 0; r < 2; ++r) {                    // grid exact: 2500 blocks
        int idx = (blockIdx.x * 4 + w) * 2 + r;      // [0, 20000)
        float v = (lane < 16) ? sup[idx * 16 + lane] : 0.0f;
        // x0 = projx(expmap0(sup)): 1 wsum + analytic norm
        float n = fmaxf(sqrtf(wsum(v * v)), EPS);
        float th0 = tanhf(SQRT_C * n);
        float x0 = th0 / (SQRT_C * n) * v;
        float x0n = th0 / SQRT_C;
        if (x0n > MAXNORM) { x0 *= MAXNORM / x0n; x0n = MAXNORM; }

        float z1n;
        float z1 = hyp_linear_n<16, 68>(x0, x0n, w1t, hb1, h1n2, lane, &z1n);  // 16->64

        // HypAct(SiLU): logmap0 (norm known) -> silu -> expmap0+projx (1 wsum)
        float t1 = fminf(SQRT_C * z1n, 1.0f - 1e-7f);
        float u = atanhf(t1) / (SQRT_C * z1n) * z1;
        u = u / (1.0f + expf(-u));
        float un = fmaxf(sqrtf(wsum(u * u)), EPS);
        float th2 = tanhf(SQRT_C * un);
        float z2 = th2 / (SQRT_C * un) * u;
        float z2n = th2 / SQRT_C;
        if (z2n > MAXNORM) { z2 *= MAXNORM / z2n; z2n = MAXNORM; }
        // HypDropout eval: projx(expmap0(logmap0(z2))) == z2 exactly
        // (sqrt_c*z2n <= 0.996 < 1-1e-7: no clip can trigger) -> skip

        float z4n;
        float z4 = hyp_linear_n<64, 65>(z2, z2n, w2t, hb2, h2n2, lane, &z4n);  // 64->64
        int oidx = idx * 64 + lane;
        if (isbf) ((__hip_bfloat16*)outv)[oidx] = __float2bfloat16(z4);
        else      ((float*)outv)[oidx] = z4;
    }
}

extern "C" void kernel_launch(void* const* d_in, const int* in_sizes, int n_in,
                              void* d_out, int out_size, void* d_ws, size_t ws_size,
                              hipStream_t stream) {
    // setup_inputs order: history_graphs(0, unused), edge_index(1), emb(2),
    //                     att_i(3), att_j(4), w1(5), b1(6), w2(7), b2(8)
    const int* ei = (const int*)d_in[1];
    const void* emb   = d_in[2];
    const void* att_i = d_in[3];
    const void* att_j = d_in[4];
    const void* w1 = d_in[5];
    const void* b1 = d_in[6];
    const void* w2 = d_in[7];
    const void* b2 = d_in[8];

    // workspace layout (float words), ~5.05 MB total
    float* ws = (float*)d_ws;
    float* xt  = ws;                                  // [10000][64]
    float* ai  = ws + 640000;                         // [10000][4]
    float* aj  = ws + 680000;                         // [10000][4]
    float* sup = ws + 720000;                         // [2][10000][16]
    int* cnt   = (int*)(ws + 1040000);                // [2][10000]
    int* off   = (int*)(ws + 1060000);                // [2][10000]
    int* cur   = (int*)(ws + 1080000);                // [2][10000]
    unsigned short* bucket = (unsigned short*)(ws + 1100000);  // [320000] u16
    int* flag  = (int*)(ws + 1260000);                // dtype flag

    hipLaunchKernelGGL(init_sniff, dim3(79), dim3(256), 0, stream,
                       cnt, (const unsigned*)emb, flag);
    hipLaunchKernelGGL(pre_count, dim3(3750), dim3(256), 0, stream,
                       emb, att_i, att_j, flag, ei, xt, ai, aj, cnt);
    hipLaunchKernelGGL(scan_offsets, dim3(1), dim3(1024), 0, stream, cnt, off, cur);
    hipLaunchKernelGGL(edge_scatter, dim3(1250), dim3(256), 0, stream, ei, cur, bucket);
    hipLaunchKernelGGL(node_agg, dim3(5000), dim3(256), 0, stream,
                       off, cur, bucket, ai, aj, xt, sup);
    hipLaunchKernelGGL(final_stage, dim3(2500), dim3(256), 0, stream,
                       sup, w1, b1, w2, b2, flag, d_out);
}

// Round 5
// 237.566 us; speedup vs baseline: 2.5109x; 1.1186x over previous
//
#include <hip/hip_runtime.h>
#include <hip/hip_bf16.h>

#define N_NODES 10000
#define NE 160000
#define SQRT_C 0.1f
#define CC 0.01f
#define EPS 1e-15f
#define MAXNORM ((1.0f - 4e-3f) / SQRT_C)   // geoopt projx boundary, 9.96

// dual-dtype load: harness may hand float arrays as bf16 or float32; a sniffer
// kernel votes once and every load branches (wave-uniform) on the flag.
__device__ __forceinline__ float ldf(const void* p, int i, int isbf) {
    return isbf ? __bfloat162float(((const __hip_bfloat16*)p)[i])
                : ((const float*)p)[i];
}

// ---------- wave-wide helpers (wave64) ----------
__device__ __forceinline__ float wsum(float v) {
#pragma unroll
    for (int off = 32; off > 0; off >>= 1) v += __shfl_xor(v, off, 64);
    return v;
}

// ---------- kernel 0: zero per-node counters + sniff float dtype ----------
__global__ __launch_bounds__(256) void init_sniff(int* __restrict__ cnt,
                                                  const unsigned* __restrict__ embw,
                                                  int* __restrict__ flag) {
    int t = blockIdx.x * 256 + threadIdx.x;
    if (t < 2 * N_NODES) cnt[t] = 0;
    if (blockIdx.x == 0 && threadIdx.x < 64) {   // one full wave
        unsigned w = embw[threadIdx.x];
        unsigned e = (w >> 7) & 0xFFu;           // exponent of low-half bf16
        unsigned long long m = __ballot(e >= 116u && e <= 133u);
        if (threadIdx.x == 0) *flag = (__popcll(m) >= 32) ? 1 : 0;
    }
}

// only graphs 3 (b=0) and 7 (b=1) reach the output (last-timestep slice)
#define EDGE_PREAMBLE(T)                                                  \
    int slot = ((T) >= NE) ? 1 : 0;                                       \
    int e = (T) - slot * NE;                                              \
    int g = slot ? 7 : 3;

// ---------- kernel 1: fused node features + edge counting + weight convert ----------
// blocks [0,2500): wave-per-node tangent features + attention dots
// blocks [2500,3750): per-(slot,src) edge counts
// block 3750: convert w1/w2/b1/b2 to fp32 (+ hyperbolic biases) for final_stage
__global__ __launch_bounds__(256) void pre_count(const void* __restrict__ emb,
                                                 const void* __restrict__ att_i,
                                                 const void* __restrict__ att_j,
                                                 const void* __restrict__ w1g,
                                                 const void* __restrict__ b1g,
                                                 const void* __restrict__ w2g,
                                                 const void* __restrict__ b2g,
                                                 const int* __restrict__ flag,
                                                 const int* __restrict__ ei,
                                                 float* __restrict__ xt,
                                                 float* __restrict__ ai,
                                                 float* __restrict__ aj,
                                                 int* __restrict__ cnt,
                                                 float* __restrict__ wf1,
                                                 float* __restrict__ wf2,
                                                 float* __restrict__ hb1f,
                                                 float* __restrict__ hb2f,
                                                 float* __restrict__ hbn2) {
    if (blockIdx.x < 2500) {
        int isbf = *flag;
        int t = blockIdx.x * 256 + threadIdx.x;   // 10000*64 threads exact
        int node = t >> 6;
        int lane = t & 63;
        float u = ldf(emb, node * 64 + lane, isbf);
        // xt = logmap0(projx(expmap0(u))): one wsum, then analytic norms
        float n = fmaxf(sqrtf(wsum(u * u)), EPS);
        float th = tanhf(SQRT_C * n);
        float x0 = th / (SQRT_C * n) * u;
        float x0n = th / SQRT_C;
        if (x0n > MAXNORM) { x0 *= MAXNORM / x0n; x0n = MAXNORM; }
        float tc = fminf(SQRT_C * x0n, 1.0f - 1e-7f);
        float xv = atanhf(tc) / (SQRT_C * x0n) * x0;
        xt[node * 64 + lane] = xv;
        float pi = xv * ldf(att_i, lane, isbf);
        float pj = xv * ldf(att_j, lane, isbf);
#pragma unroll
        for (int off = 8; off > 0; off >>= 1) {   // aligned 16-lane head groups
            pi += __shfl_xor(pi, off, 64);
            pj += __shfl_xor(pj, off, 64);
        }
        if ((lane & 15) == 0) {
            ai[node * 4 + (lane >> 4)] = pi;
            aj[node * 4 + (lane >> 4)] = pj;
        }
    } else if (blockIdx.x < 3750) {
        int t = (blockIdx.x - 2500) * 256 + threadIdx.x;   // 2*NE exact
        EDGE_PREAMBLE(t);
        int src = ei[g * 2 * NE + e];
        atomicAdd(&cnt[slot * N_NODES + src], 1);
    } else {
        int isbf = *flag;
        int tid = threadIdx.x;
        for (int i = tid; i < 1024; i += 256) wf1[i] = ldf(w1g, i, isbf);
        for (int i = tid; i < 4096; i += 256) wf2[i] = ldf(w2g, i, isbf);
        int w = tid >> 6, lane = tid & 63;
        if (w < 2) {                               // hb = projx(expmap0(b)), + norm^2
            const void* bg = w ? b2g : b1g;
            float b = ldf(bg, lane, isbf);
            float n = fmaxf(sqrtf(wsum(b * b)), EPS);
            float th = tanhf(SQRT_C * n);
            float hv = th / (SQRT_C * n) * b;
            float hn = th / SQRT_C;
            if (hn > MAXNORM) { hv *= MAXNORM / hn; hn = MAXNORM; }
            (w ? hb2f : hb1f)[lane] = hv;
            if (lane == 0) hbn2[w] = hn * hn;
        }
    }
}

// ---------- kernel 2: coalesced exclusive scan over 20000 counts (1 block) ----------
// 20 chunked block-scans of 1024 with a running carry; all loads/stores coalesced.
__global__ __launch_bounds__(1024) void scan_offsets(const int* __restrict__ cnt,
                                                     int* __restrict__ off,
                                                     int* __restrict__ cur) {
    __shared__ int wpart[16];
    __shared__ int btot;
    const int TOT = 2 * N_NODES;
    int t = threadIdx.x, lane = t & 63, w = t >> 6;
    int carry = 0;
    for (int k = 0; k < 20; ++k) {
        int idx = k * 1024 + t;
        int v = (idx < TOT) ? cnt[idx] : 0;
        int inc = v;                               // inclusive wave scan
#pragma unroll
        for (int o = 1; o < 64; o <<= 1) {
            int u = __shfl_up(inc, o, 64);
            if (lane >= o) inc += u;
        }
        if (lane == 63) wpart[w] = inc;
        __syncthreads();
        if (w == 0) {
            int p = (lane < 16) ? wpart[lane] : 0;
            int ip = p;
#pragma unroll
            for (int o = 1; o < 16; o <<= 1) {
                int u = __shfl_up(ip, o, 64);
                if (lane >= o) ip += u;
            }
            if (lane < 16) wpart[lane] = ip - p;   // exclusive wave prefix
            if (lane == 15) btot = ip;             // chunk total
        }
        __syncthreads();
        int exc = carry + wpart[w] + inc - v;
        if (idx < TOT) { off[idx] = exc; cur[idx] = exc; }
        carry += btot;
        __syncthreads();                           // protect wpart/btot reuse
    }
}

// ---------- kernel 3: scatter dst ids into src-grouped buckets ----------
__global__ __launch_bounds__(256) void edge_scatter(const int* __restrict__ ei,
                                                    int* __restrict__ cur,
                                                    unsigned short* __restrict__ bucket) {
    int t = blockIdx.x * 256 + threadIdx.x;   // 2*NE exact
    EDGE_PREAMBLE(t);
    int src = ei[g * 2 * NE + e];
    int dst = ei[g * 2 * NE + NE + e];
    int pos = atomicAdd(&cur[slot * N_NODES + src], 1);
    bucket[pos] = (unsigned short)dst;
}

// ---------- kernel 4: per-node softmax + aggregation, atomic-free ----------
// writes sup TRANSPOSED: sup_t[c*20000 + idx] so final_stage loads coalesce.
__global__ __launch_bounds__(256) void node_agg(const int* __restrict__ off,
                                                const int* __restrict__ cur,
                                                const unsigned short* __restrict__ bucket,
                                                const float* __restrict__ ai,
                                                const float* __restrict__ aj,
                                                const float* __restrict__ xt,
                                                float* __restrict__ sup_t) {
    int w = threadIdx.x >> 6, lane = threadIdx.x & 63;
    int idx = blockIdx.x * 4 + w;          // grid exact: 20000 waves
    int n = (idx >= N_NODES) ? idx - N_NODES : idx;
    int start = off[idx], end = cur[idx];

    float ain[4], ajn[4];
#pragma unroll
    for (int h = 0; h < 4; ++h) { ain[h] = ai[n * 4 + h]; ajn[h] = aj[n * 4 + h]; }

    // phase A: per-head max (self-loop in every lane; max is idempotent)
    float mh[4];
#pragma unroll
    for (int h = 0; h < 4; ++h) {
        float a = ain[h] + ajn[h];
        mh[h] = (a < 0.0f) ? 0.2f * a : a;
    }
    for (int e = start + lane; e < end; e += 64) {
        int d = bucket[e];
#pragma unroll
        for (int h = 0; h < 4; ++h) {
            float a = ain[h] + aj[d * 4 + h];
            a = (a < 0.0f) ? 0.2f * a : a;
            mh[h] = fmaxf(mh[h], a);
        }
    }
#pragma unroll
    for (int h = 0; h < 4; ++h)
#pragma unroll
        for (int o = 32; o > 0; o >>= 1) mh[h] = fmaxf(mh[h], __shfl_xor(mh[h], o, 64));

    // phase B: per-head sum of exp(alpha - m) (self-loop once, lane 0)
    float sh[4] = {0.f, 0.f, 0.f, 0.f};
    if (lane == 0) {
#pragma unroll
        for (int h = 0; h < 4; ++h) {
            float a = ain[h] + ajn[h];
            a = (a < 0.0f) ? 0.2f * a : a;
            sh[h] = expf(a - mh[h]);
        }
    }
    for (int e = start + lane; e < end; e += 64) {
        int d = bucket[e];
#pragma unroll
        for (int h = 0; h < 4; ++h) {
            float a = ain[h] + aj[d * 4 + h];
            a = (a < 0.0f) ? 0.2f * a : a;
            sh[h] += expf(a - mh[h]);
        }
    }
#pragma unroll
    for (int h = 0; h < 4; ++h) sh[h] = wsum(sh[h]);
    float scale[4];
#pragma unroll
    for (int h = 0; h < 4; ++h) scale[h] = 0.25f / (sh[h] + 1e-16f);

    // phase C: whole-wave weighted gather; lane = h*16 + c
    int hh = lane >> 4;
    float aih = ain[hh], mhh = mh[hh], sch = scale[hh];
    float aself = aih + ajn[hh];
    aself = (aself < 0.0f) ? 0.2f * aself : aself;
    float acc = expf(aself - mhh) * sch * xt[n * 64 + lane];
    for (int e = start; e < end; ++e) {
        int d = bucket[e];                 // wave-uniform scalar
        float a = aih + aj[d * 4 + hh];
        a = (a < 0.0f) ? 0.2f * a : a;
        acc = fmaf(expf(a - mhh) * sch, xt[d * 64 + lane], acc);
    }
    acc += __shfl_xor(acc, 16, 64);        // head mean (x0.25 in scale)
    acc += __shfl_xor(acc, 32, 64);
    if (lane < 16) sup_t[lane * 20000 + idx] = acc;
}

// ---------- kernel 5: hyperbolic head, NODE-PER-LANE ----------
// lane = one (slot,node); all norms/reductions are per-lane register math.
// Weights are wave-uniform -> scalar loads (off the LDS & VMEM vector pipes).
// Output transposed through padded LDS tile for coalesced stores.
__global__ __launch_bounds__(128) void final_stage(const float* __restrict__ sup_t,
                                                   const float* __restrict__ wf1,
                                                   const float* __restrict__ wf2,
                                                   const float* __restrict__ hb1f,
                                                   const float* __restrict__ hb2f,
                                                   const float* __restrict__ hbn2,
                                                   const int* __restrict__ flag,
                                                   void* __restrict__ outv) {
    __shared__ float tile[2][64 * 65];     // stride 65: 2-way banks, free
    __shared__ float sarr[2][64];
    int w = threadIdx.x >> 6, lane = threadIdx.x & 63;
    float* T = tile[w];
    int base = (blockIdx.x * 2 + w) * 64;  // grid: 157 blocks x 128 -> 314 waves
    int idx = base + lane;
    bool valid = (idx < 2 * N_NODES);
    int isbf = *flag;
    float y2a = hbn2[0], y2b = hbn2[1];

    // x0 = projx(expmap0(sup)), 16-dim, per-lane
    float v[16];
#pragma unroll
    for (int c = 0; c < 16; ++c) v[c] = valid ? sup_t[c * 20000 + idx] : 0.0f;
    float n2 = 0.f;
#pragma unroll
    for (int c = 0; c < 16; ++c) n2 = fmaf(v[c], v[c], n2);
    float n = fmaxf(sqrtf(n2), EPS);
    float th0 = tanhf(SQRT_C * n);
    float s0 = th0 / (SQRT_C * n);
    float x0n = th0 / SQRT_C;
    if (x0n > MAXNORM) { s0 *= MAXNORM / x0n; x0n = MAXNORM; }
#pragma unroll
    for (int c = 0; c < 16; ++c) v[c] *= s0;

    // ---- hyp_linear 1 (16 -> 64), fully unrolled, mx in registers ----
    float mx[64];
    float mxn2 = 0.f, mxhb = 0.f;
#pragma unroll
    for (int o = 0; o < 64; ++o) {
        float a = 0.f;
#pragma unroll
        for (int c = 0; c < 16; ++c) a = fmaf(wf1[o * 16 + c], v[c], a);
        mx[o] = a;
        mxn2 = fmaf(a, a, mxn2);
        mxhb = fmaf(a, hb1f[o], mxhb);
    }
    {
        float xn = fmaxf(x0n, EPS);
        float mxn = fmaxf(sqrtf(mxn2), EPS);
        float t = fminf(SQRT_C * xn, 1.0f - 1e-7f);
        float th = tanhf(mxn / xn * atanhf(t));
        float rs = th / (mxn * SQRT_C);    // res = rs * mx
        float rn = th / SQRT_C;
        if (mxn2 == 0.0f) { rs = 0.f; rn = 0.f; }     // all(mx==0) guard
        if (rn > MAXNORM) { rs *= MAXNORM / rn; rn = MAXNORM; }
        float xy = rs * mxhb;              // <res,hb> = rs * <mx,hb>
        float x2 = rn * rn;
        float A = 1.0f + 2.0f * CC * xy + CC * y2a;
        float B = 1.0f - CC * x2;
        float rden = 1.0f / fmaxf(1.0f + 2.0f * CC * xy + CC * CC * x2 * y2a, EPS);
        float zn2 = 0.f;
#pragma unroll
        for (int o = 0; o < 64; ++o) {
            float z = (A * rs * mx[o] + B * hb1f[o]) * rden;
            mx[o] = z;
            zn2 = fmaf(z, z, zn2);
        }
        float zn = fmaxf(sqrtf(zn2), EPS);
        float sc = (zn > MAXNORM) ? MAXNORM / zn : 1.0f;
        float z1n = fminf(zn, MAXNORM);
        // HypAct(SiLU): u = logmap0(z1) -> silu -> expmap0+projx
        float lg = atanhf(fminf(SQRT_C * z1n, 1.0f - 1e-7f)) / (SQRT_C * z1n) * sc;
        float un2 = 0.f;
#pragma unroll
        for (int o = 0; o < 64; ++o) {
            float u = lg * mx[o];
            u = u / (1.0f + expf(-u));
            mx[o] = u;
            un2 = fmaf(u, u, un2);
        }
        float un = fmaxf(sqrtf(un2), EPS);
        float th2 = tanhf(SQRT_C * un);
        float s2 = th2 / (SQRT_C * un);
        float z2n = th2 / SQRT_C;
        if (z2n > MAXNORM) { s2 *= MAXNORM / z2n; z2n = MAXNORM; }
#pragma unroll
        for (int o = 0; o < 64; ++o) mx[o] *= s2;     // z2 in mx[]
        x0n = z2n;                                    // carry norm into hyp2
        // HypDropout eval: projx(expmap0(logmap0(z2))) == z2 exactly (no clip
        // can trigger: sqrt_c*z2n <= 0.996 < 1-1e-7) -> skip
    }

    // ---- hyp_linear 2 (64 -> 64), rolled over o, mx2 staged in LDS ----
    float mxn2b = 0.f, mxhb2 = 0.f;
#pragma unroll 2
    for (int o = 0; o < 64; ++o) {
        float a = 0.f;
#pragma unroll
        for (int c = 0; c < 64; ++c) a = fmaf(wf2[o * 64 + c], mx[c], a);
        T[lane * 65 + o] = a;
        mxn2b = fmaf(a, a, mxn2b);
        mxhb2 = fmaf(a, hb2f[o], mxhb2);
    }
    {
        float xn = fmaxf(x0n, EPS);
        float mxn = fmaxf(sqrtf(mxn2b), EPS);
        float t = fminf(SQRT_C * xn, 1.0f - 1e-7f);
        float th = tanhf(mxn / xn * atanhf(t));
        float rs = th / (mxn * SQRT_C);
        float rn = th / SQRT_C;
        if (mxn2b == 0.0f) { rs = 0.f; rn = 0.f; }
        if (rn > MAXNORM) { rs *= MAXNORM / rn; rn = MAXNORM; }
        float xy = rs * mxhb2;
        float x2 = rn * rn;
        float A = 1.0f + 2.0f * CC * xy + CC * y2b;
        float B = 1.0f - CC * x2;
        float rden = 1.0f / fmaxf(1.0f + 2.0f * CC * xy + CC * CC * x2 * y2b, EPS);
        float zn2 = 0.f;
#pragma unroll 4
        for (int o = 0; o < 64; ++o) {
            float z = (A * rs * T[lane * 65 + o] + B * hb2f[o]) * rden;
            T[lane * 65 + o] = z;
            zn2 = fmaf(z, z, zn2);
        }
        float zn = fmaxf(sqrtf(zn2), EPS);
        sarr[w][lane] = (zn > MAXNORM) ? MAXNORM / zn : 1.0f;   // final projx scale
    }
    __syncthreads();

    // transpose out of LDS: coalesced stores, per-node projx scale applied
    if (isbf) {
        __hip_bfloat16* out = (__hip_bfloat16*)outv;
#pragma unroll 4
        for (int nn = 0; nn < 64; ++nn) {
            int node = base + nn;
            if (node >= 2 * N_NODES) break;
            float val = T[nn * 65 + lane] * sarr[w][nn];
            out[node * 64 + lane] = __float2bfloat16(val);
        }
    } else {
        float* out = (float*)outv;
#pragma unroll 4
        for (int nn = 0; nn < 64; ++nn) {
            int node = base + nn;
            if (node >= 2 * N_NODES) break;
            out[node * 64 + lane] = T[nn * 65 + lane] * sarr[w][nn];
        }
    }
}

extern "C" void kernel_launch(void* const* d_in, const int* in_sizes, int n_in,
                              void* d_out, int out_size, void* d_ws, size_t ws_size,
                              hipStream_t stream) {
    // setup_inputs order: history_graphs(0, unused), edge_index(1), emb(2),
    //                     att_i(3), att_j(4), w1(5), b1(6), w2(7), b2(8)
    const int* ei = (const int*)d_in[1];
    const void* emb   = d_in[2];
    const void* att_i = d_in[3];
    const void* att_j = d_in[4];
    const void* w1 = d_in[5];
    const void* b1 = d_in[6];
    const void* w2 = d_in[7];
    const void* b2 = d_in[8];

    // workspace layout (float words), ~5.06 MB total
    float* ws = (float*)d_ws;
    float* xt    = ws;                                // [10000][64]
    float* ai    = ws + 640000;                       // [10000][4]
    float* aj    = ws + 680000;                       // [10000][4]
    float* sup_t = ws + 720000;                       // [16][20000] transposed
    int* cnt   = (int*)(ws + 1040000);                // [2][10000]
    int* off   = (int*)(ws + 1060000);                // [2][10000]
    int* cur   = (int*)(ws + 1080000);                // [2][10000]
    unsigned short* bucket = (unsigned short*)(ws + 1100000);  // [320000] u16
    int* flag  = (int*)(ws + 1260000);                // dtype flag
    float* wf1  = ws + 1260064;                       // [64][16] fp32
    float* wf2  = ws + 1261088;                       // [64][64] fp32
    float* hb1f = ws + 1265184;                       // [64]
    float* hb2f = ws + 1265248;                       // [64]
    float* hbn2 = ws + 1265312;                       // [2]

    hipLaunchKernelGGL(init_sniff, dim3(79), dim3(256), 0, stream,
                       cnt, (const unsigned*)emb, flag);
    hipLaunchKernelGGL(pre_count, dim3(3751), dim3(256), 0, stream,
                       emb, att_i, att_j, w1, b1, w2, b2, flag, ei,
                       xt, ai, aj, cnt, wf1, wf2, hb1f, hb2f, hbn2);
    hipLaunchKernelGGL(scan_offsets, dim3(1), dim3(1024), 0, stream, cnt, off, cur);
    hipLaunchKernelGGL(edge_scatter, dim3(1250), dim3(256), 0, stream, ei, cur, bucket);
    hipLaunchKernelGGL(node_agg, dim3(5000), dim3(256), 0, stream,
                       off, cur, bucket, ai, aj, xt, sup_t);
    hipLaunchKernelGGL(final_stage, dim3(157), dim3(128), 0, stream,
                       sup_t, wf1, wf2, hb1f, hb2f, hbn2, flag, d_out);
}

// Round 6
// 187.923 us; speedup vs baseline: 3.1742x; 1.2642x over previous
//
#include <hip/hip_runtime.h>
#include <hip/hip_bf16.h>

#define N_NODES 10000
#define NE 160000
#define SQRT_C 0.1f
#define CC 0.01f
#define EPS 1e-15f
#define MAXNORM ((1.0f - 4e-3f) / SQRT_C)   // geoopt projx boundary, 9.96

// dual-dtype load: harness may hand float arrays as bf16 or float32; a sniffer
// kernel votes once and every load branches (wave-uniform) on the flag.
__device__ __forceinline__ float ldf(const void* p, int i, int isbf) {
    return isbf ? __bfloat162float(((const __hip_bfloat16*)p)[i])
                : ((const float*)p)[i];
}

// ---------- wave-wide helpers (wave64) ----------
__device__ __forceinline__ float wsum(float v) {
#pragma unroll
    for (int off = 32; off > 0; off >>= 1) v += __shfl_xor(v, off, 64);
    return v;
}
__device__ __forceinline__ float wmax(float v) {
#pragma unroll
    for (int off = 32; off > 0; off >>= 1) v = fmaxf(v, __shfl_xor(v, off, 64));
    return v;
}

// ---------- kernel 0: zero per-node counters + sniff float dtype ----------
__global__ __launch_bounds__(256) void init_sniff(int* __restrict__ cnt,
                                                  const unsigned* __restrict__ embw,
                                                  int* __restrict__ flag) {
    int t = blockIdx.x * 256 + threadIdx.x;
    if (t < 2 * N_NODES) cnt[t] = 0;
    if (blockIdx.x == 0 && threadIdx.x < 64) {   // one full wave
        unsigned w = embw[threadIdx.x];
        unsigned e = (w >> 7) & 0xFFu;           // exponent of low-half bf16
        unsigned long long m = __ballot(e >= 116u && e <= 133u);
        if (threadIdx.x == 0) *flag = (__popcll(m) >= 32) ? 1 : 0;
    }
}

// only graphs 3 (b=0) and 7 (b=1) reach the output (last-timestep slice)
#define EDGE_PREAMBLE(T)                                                  \
    int slot = ((T) >= NE) ? 1 : 0;                                       \
    int e = (T) - slot * NE;                                              \
    int g = slot ? 7 : 3;

// ---------- kernel 1: fused node features + edge counting + weight convert ----------
// blocks [0,2500): wave-per-node tangent features + attention dots
// blocks [2500,3750): per-(slot,src) edge counts
// block 3750: convert weights to fp32 TRANSPOSED (c-major) + hyperbolic biases
__global__ __launch_bounds__(256) void pre_count(const void* __restrict__ emb,
                                                 const void* __restrict__ att_i,
                                                 const void* __restrict__ att_j,
                                                 const void* __restrict__ w1g,
                                                 const void* __restrict__ b1g,
                                                 const void* __restrict__ w2g,
                                                 const void* __restrict__ b2g,
                                                 const int* __restrict__ flag,
                                                 const int* __restrict__ ei,
                                                 float* __restrict__ xt,
                                                 float* __restrict__ ai,
                                                 float* __restrict__ aj,
                                                 int* __restrict__ cnt,
                                                 float* __restrict__ wf1t,
                                                 float* __restrict__ wf2t,
                                                 float* __restrict__ hb1f,
                                                 float* __restrict__ hb2f,
                                                 float* __restrict__ hbn2) {
    if (blockIdx.x < 2500) {
        int isbf = *flag;
        int t = blockIdx.x * 256 + threadIdx.x;   // 10000*64 threads exact
        int node = t >> 6;
        int lane = t & 63;
        float u = ldf(emb, node * 64 + lane, isbf);
        // xt = logmap0(projx(expmap0(u))): one wsum, then analytic norms
        float n = fmaxf(sqrtf(wsum(u * u)), EPS);
        float th = tanhf(SQRT_C * n);
        float x0 = th / (SQRT_C * n) * u;
        float x0n = th / SQRT_C;
        if (x0n > MAXNORM) { x0 *= MAXNORM / x0n; x0n = MAXNORM; }
        float tc = fminf(SQRT_C * x0n, 1.0f - 1e-7f);
        float xv = atanhf(tc) / (SQRT_C * x0n) * x0;
        xt[node * 64 + lane] = xv;
        float pi = xv * ldf(att_i, lane, isbf);
        float pj = xv * ldf(att_j, lane, isbf);
#pragma unroll
        for (int off = 8; off > 0; off >>= 1) {   // aligned 16-lane head groups
            pi += __shfl_xor(pi, off, 64);
            pj += __shfl_xor(pj, off, 64);
        }
        if ((lane & 15) == 0) {
            ai[node * 4 + (lane >> 4)] = pi;
            aj[node * 4 + (lane >> 4)] = pj;
        }
    } else if (blockIdx.x < 3750) {
        int t = (blockIdx.x - 2500) * 256 + threadIdx.x;   // 2*NE exact
        EDGE_PREAMBLE(t);
        int src = ei[g * 2 * NE + e];
        atomicAdd(&cnt[slot * N_NODES + src], 1);
    } else {
        int isbf = *flag;
        int tid = threadIdx.x;
        for (int i = tid; i < 1024; i += 256) {            // w1[o][c] -> wf1t[c*64+o]
            int o = i >> 4, c = i & 15;
            wf1t[c * 64 + o] = ldf(w1g, i, isbf);
        }
        for (int i = tid; i < 4096; i += 256) {            // w2[o][c] -> wf2t[c*64+o]
            int o = i >> 6, c = i & 63;
            wf2t[c * 64 + o] = ldf(w2g, i, isbf);
        }
        int w = tid >> 6, lane = tid & 63;
        if (w < 2) {                               // hb = projx(expmap0(b)), + norm^2
            const void* bg = w ? b2g : b1g;
            float b = ldf(bg, lane, isbf);
            float n = fmaxf(sqrtf(wsum(b * b)), EPS);
            float th = tanhf(SQRT_C * n);
            float hv = th / (SQRT_C * n) * b;
            float hn = th / SQRT_C;
            if (hn > MAXNORM) { hv *= MAXNORM / hn; hn = MAXNORM; }
            (w ? hb2f : hb1f)[lane] = hv;
            if (lane == 0) hbn2[w] = hn * hn;
        }
    }
}

// ---------- kernel 2: coalesced exclusive scan over 20000 counts (1 block) ----------
__global__ __launch_bounds__(1024) void scan_offsets(const int* __restrict__ cnt,
                                                     int* __restrict__ off,
                                                     int* __restrict__ cur) {
    __shared__ int wpart[16];
    __shared__ int btot;
    const int TOT = 2 * N_NODES;
    int t = threadIdx.x, lane = t & 63, w = t >> 6;
    int carry = 0;
    for (int k = 0; k < 20; ++k) {
        int idx = k * 1024 + t;
        int v = (idx < TOT) ? cnt[idx] : 0;
        int inc = v;                               // inclusive wave scan
#pragma unroll
        for (int o = 1; o < 64; o <<= 1) {
            int u = __shfl_up(inc, o, 64);
            if (lane >= o) inc += u;
        }
        if (lane == 63) wpart[w] = inc;
        __syncthreads();
        if (w == 0) {
            int p = (lane < 16) ? wpart[lane] : 0;
            int ip = p;
#pragma unroll
            for (int o = 1; o < 16; o <<= 1) {
                int u = __shfl_up(ip, o, 64);
                if (lane >= o) ip += u;
            }
            if (lane < 16) wpart[lane] = ip - p;   // exclusive wave prefix
            if (lane == 15) btot = ip;             // chunk total
        }
        __syncthreads();
        int exc = carry + wpart[w] + inc - v;
        if (idx < TOT) { off[idx] = exc; cur[idx] = exc; }
        carry += btot;
        __syncthreads();                           // protect wpart/btot reuse
    }
}

// ---------- kernel 3: scatter dst ids into src-grouped buckets ----------
__global__ __launch_bounds__(256) void edge_scatter(const int* __restrict__ ei,
                                                    int* __restrict__ cur,
                                                    unsigned short* __restrict__ bucket) {
    int t = blockIdx.x * 256 + threadIdx.x;   // 2*NE exact
    EDGE_PREAMBLE(t);
    int src = ei[g * 2 * NE + e];
    int dst = ei[g * 2 * NE + NE + e];
    int pos = atomicAdd(&cur[slot * N_NODES + src], 1);
    bucket[pos] = (unsigned short)dst;
}

// ---------- kernel 4: per-node softmax + aggregation, atomic-free ----------
// fast path (deg<=63): edge-per-lane softmax (1 exp per edge), weights staged
// in LDS, then a minimal gather loop. Self-loop handled as lane==cnt.
__global__ __launch_bounds__(256) void node_agg(const int* __restrict__ off,
                                                const int* __restrict__ cur,
                                                const unsigned short* __restrict__ bucket,
                                                const float* __restrict__ ai,
                                                const float* __restrict__ aj,
                                                const float* __restrict__ xt,
                                                float* __restrict__ sup_t) {
    __shared__ float wlds[4][64 * 4];
    __shared__ int dlds[4][64];
    int w = threadIdx.x >> 6, lane = threadIdx.x & 63;
    int idx = blockIdx.x * 4 + w;          // grid exact: 20000 waves
    int n = (idx >= N_NODES) ? idx - N_NODES : idx;
    int start = off[idx];
    int cnt = cur[idx] - start;

    float4 ai4 = *(const float4*)&ai[n * 4];
    float4 aj4n = *(const float4*)&aj[n * 4];
    float ain[4] = {ai4.x, ai4.y, ai4.z, ai4.w};
    float ajn[4] = {aj4n.x, aj4n.y, aj4n.z, aj4n.w};
    int hh = lane >> 4;
    float acc;

    if (cnt <= 63) {
        bool act = (lane <= cnt);                  // lane==cnt is the self-loop
        int d = (lane < cnt) ? (int)bucket[start + lane] : n;
        float4 a4 = act ? *(const float4*)&aj[d * 4] : make_float4(0.f, 0.f, 0.f, 0.f);
        float ajv[4] = {a4.x, a4.y, a4.z, a4.w};
        float al[4], mh[4], eh[4];
#pragma unroll
        for (int h = 0; h < 4; ++h) {
            float a = ain[h] + ajv[h];
            a = (a < 0.0f) ? 0.2f * a : a;
            al[h] = act ? a : -1e30f;
            mh[h] = al[h];
        }
#pragma unroll
        for (int h = 0; h < 4; ++h) mh[h] = wmax(mh[h]);
#pragma unroll
        for (int h = 0; h < 4; ++h) eh[h] = act ? expf(al[h] - mh[h]) : 0.0f;
        float sh[4];
#pragma unroll
        for (int h = 0; h < 4; ++h) sh[h] = wsum(eh[h]);
#pragma unroll
        for (int h = 0; h < 4; ++h)
            wlds[w][lane * 4 + h] = eh[h] * (0.25f / (sh[h] + 1e-16f));
        dlds[w][lane] = d;
        // gather: per edge e: 2 LDS broadcast reads + 1 coalesced load + 1 fma
        acc = 0.0f;
        for (int e = 0; e <= cnt; ++e) {
            int dd = dlds[w][e];
            float wgt = wlds[w][e * 4 + hh];
            acc = fmaf(wgt, xt[dd * 64 + lane], acc);
        }
    } else {
        // slow path: 3-phase strided loops (correct for any degree)
        float mh[4];
#pragma unroll
        for (int h = 0; h < 4; ++h) {
            float a = ain[h] + ajn[h];
            mh[h] = (a < 0.0f) ? 0.2f * a : a;
        }
        for (int e = start + lane; e < start + cnt; e += 64) {
            int d = bucket[e];
#pragma unroll
            for (int h = 0; h < 4; ++h) {
                float a = ain[h] + aj[d * 4 + h];
                a = (a < 0.0f) ? 0.2f * a : a;
                mh[h] = fmaxf(mh[h], a);
            }
        }
#pragma unroll
        for (int h = 0; h < 4; ++h) mh[h] = wmax(mh[h]);
        float sh[4] = {0.f, 0.f, 0.f, 0.f};
        if (lane == 0) {
#pragma unroll
            for (int h = 0; h < 4; ++h) {
                float a = ain[h] + ajn[h];
                a = (a < 0.0f) ? 0.2f * a : a;
                sh[h] = expf(a - mh[h]);
            }
        }
        for (int e = start + lane; e < start + cnt; e += 64) {
            int d = bucket[e];
#pragma unroll
            for (int h = 0; h < 4; ++h) {
                float a = ain[h] + aj[d * 4 + h];
                a = (a < 0.0f) ? 0.2f * a : a;
                sh[h] += expf(a - mh[h]);
            }
        }
#pragma unroll
        for (int h = 0; h < 4; ++h) sh[h] = wsum(sh[h]);
        float scale[4];
#pragma unroll
        for (int h = 0; h < 4; ++h) scale[h] = 0.25f / (sh[h] + 1e-16f);
        float aih = ain[hh], mhh = mh[hh], sch = scale[hh];
        float aself = aih + ajn[hh];
        aself = (aself < 0.0f) ? 0.2f * aself : aself;
        acc = expf(aself - mhh) * sch * xt[n * 64 + lane];
        for (int e = start; e < start + cnt; ++e) {
            int d = bucket[e];
            float a = aih + aj[d * 4 + hh];
            a = (a < 0.0f) ? 0.2f * a : a;
            acc = fmaf(expf(a - mhh) * sch, xt[d * 64 + lane], acc);
        }
    }
    acc += __shfl_xor(acc, 16, 64);        // head mean (x0.25 in scale)
    acc += __shfl_xor(acc, 32, 64);
    if (lane < 16) sup_t[lane * 20000 + idx] = acc;
}

// ---------- kernel 5: hyperbolic head, 4-wave cooperative ----------
// block = 256 thr = 4 waves, 64 nodes (node = lane). Wave w owns outputs
// o in [16w,16w+16). Per-node scalars reduced cross-wave via LDS partials
// (double-buffered, 1 barrier per round). z2 staging and output transpose
// share one aliased LDS buffer (>=1 barrier apart).
__global__ __launch_bounds__(256) void final_stage(const float* __restrict__ sup_t,
                                                   const float* __restrict__ wf1t,
                                                   const float* __restrict__ wf2t,
                                                   const float* __restrict__ hb1f,
                                                   const float* __restrict__ hb2f,
                                                   const float* __restrict__ hbn2,
                                                   const int* __restrict__ flag,
                                                   void* __restrict__ outv) {
    __shared__ float Z[65 * 64];           // z2s [c*64+node] then T [o*65+node]
    __shared__ float pA[2][4][64];         // reduction partials, buffer A
    __shared__ float pB[2][4][64];         // buffer B
    int w = threadIdx.x >> 6, lane = threadIdx.x & 63;
    int base = blockIdx.x * 64;            // grid: 313 blocks
    int nd = base + lane;
    bool valid = (nd < 2 * N_NODES);
    int isbf = *flag;
    float y2a = hbn2[0], y2b = hbn2[1];
    int ob = w * 16;                       // owned output base

    // x0 = projx(expmap0(sup)), computed redundantly per wave (coalesced loads)
    float v[16];
#pragma unroll
    for (int c = 0; c < 16; ++c) v[c] = valid ? sup_t[c * 20000 + nd] : 0.0f;
    float n2 = 0.f;
#pragma unroll
    for (int c = 0; c < 16; ++c) n2 = fmaf(v[c], v[c], n2);
    float n = fmaxf(sqrtf(n2), EPS);
    float th0 = tanhf(SQRT_C * n);
    float s0 = th0 / (SQRT_C * n);
    float x0n = th0 / SQRT_C;
    if (x0n > MAXNORM) { s0 *= MAXNORM / x0n; x0n = MAXNORM; }
#pragma unroll
    for (int c = 0; c < 16; ++c) v[c] *= s0;

    // ---- matvec1: 16 owned outputs, 16 channels (weights: uniform s_loads) ----
    float a1[16];
#pragma unroll
    for (int oj = 0; oj < 16; ++oj) a1[oj] = 0.f;
#pragma unroll
    for (int c = 0; c < 16; ++c) {
        float vc = v[c];
#pragma unroll
        for (int oj = 0; oj < 16; ++oj)
            a1[oj] = fmaf(wf1t[c * 64 + ob + oj], vc, a1[oj]);
    }
    float pn = 0.f, ph = 0.f;              // partial |mx|^2, <mx,hb1>
#pragma unroll
    for (int oj = 0; oj < 16; ++oj) {
        pn = fmaf(a1[oj], a1[oj], pn);
        ph = fmaf(a1[oj], hb1f[ob + oj], ph);
    }
    // R1 (buf A): reduce mxn2, mxhb
    pA[0][w][lane] = pn; pA[1][w][lane] = ph;
    __syncthreads();
    float mxn2 = pA[0][0][lane] + pA[0][1][lane] + pA[0][2][lane] + pA[0][3][lane];
    float mxhb = pA[1][0][lane] + pA[1][1][lane] + pA[1][2][lane] + pA[1][3][lane];

    // mobius scalars (per node, redundant across waves)
    float z2n;                             // carried norm into matvec2
    {
        float xn = fmaxf(x0n, EPS);
        float mxn = fmaxf(sqrtf(mxn2), EPS);
        float t = fminf(SQRT_C * xn, 1.0f - 1e-7f);
        float th = tanhf(mxn / xn * atanhf(t));
        float rs = th / (mxn * SQRT_C);
        float rn = th / SQRT_C;
        if (mxn2 == 0.0f) { rs = 0.f; rn = 0.f; }        // all(mx==0) guard
        if (rn > MAXNORM) { rs *= MAXNORM / rn; rn = MAXNORM; }
        float xy = rs * mxhb;
        float x2 = rn * rn;
        float A = 1.0f + 2.0f * CC * xy + CC * y2a;
        float B = 1.0f - CC * x2;
        float rden = 1.0f / fmaxf(1.0f + 2.0f * CC * xy + CC * CC * x2 * y2a, EPS);
        float pz = 0.f;
#pragma unroll
        for (int oj = 0; oj < 16; ++oj) {
            float z = (A * rs * a1[oj] + B * hb1f[ob + oj]) * rden;
            a1[oj] = z;
            pz = fmaf(z, z, pz);
        }
        // R2 (buf B): reduce zn2
        pB[0][w][lane] = pz;
        __syncthreads();
        float zn2 = pB[0][0][lane] + pB[0][1][lane] + pB[0][2][lane] + pB[0][3][lane];
        float zn = fmaxf(sqrtf(zn2), EPS);
        float sc = (zn > MAXNORM) ? MAXNORM / zn : 1.0f;
        float z1n = fminf(zn, MAXNORM);
        // HypAct(SiLU): u = logmap0(z1) -> silu
        float lg = atanhf(fminf(SQRT_C * z1n, 1.0f - 1e-7f)) / (SQRT_C * z1n) * sc;
        float pu = 0.f;
#pragma unroll
        for (int oj = 0; oj < 16; ++oj) {
            float u = lg * a1[oj];
            u = u / (1.0f + expf(-u));
            a1[oj] = u;
            pu = fmaf(u, u, pu);
        }
        // R3 (buf A): reduce un2
        pA[0][w][lane] = pu;
        __syncthreads();
        float un2 = pA[0][0][lane] + pA[0][1][lane] + pA[0][2][lane] + pA[0][3][lane];
        float un = fmaxf(sqrtf(un2), EPS);
        float th2 = tanhf(SQRT_C * un);
        float s2 = th2 / (SQRT_C * un);
        z2n = th2 / SQRT_C;
        if (z2n > MAXNORM) { s2 *= MAXNORM / z2n; z2n = MAXNORM; }
        // stage z2 into LDS [c*64 + node]
#pragma unroll
        for (int oj = 0; oj < 16; ++oj) Z[(ob + oj) * 64 + lane] = a1[oj] * s2;
        // HypDropout eval round-trip == identity (no clip possible) -> skip
    }
    __syncthreads();                       // z2s ready for all waves

    // ---- matvec2: 16 owned outputs, 64 channels (z2 via LDS, weights s_load) ----
    float a2[16];
#pragma unroll
    for (int oj = 0; oj < 16; ++oj) a2[oj] = 0.f;
#pragma unroll 4
    for (int c = 0; c < 64; ++c) {
        float zc = Z[c * 64 + lane];
#pragma unroll
        for (int oj = 0; oj < 16; ++oj)
            a2[oj] = fmaf(wf2t[c * 64 + ob + oj], zc, a2[oj]);
    }
    float pn2 = 0.f, ph2 = 0.f;
#pragma unroll
    for (int oj = 0; oj < 16; ++oj) {
        pn2 = fmaf(a2[oj], a2[oj], pn2);
        ph2 = fmaf(a2[oj], hb2f[ob + oj], ph2);
    }
    // R4 (buf B): reduce mxn2b, mxhb2  (also separates z2s reads from T writes)
    pB[0][w][lane] = pn2; pB[1][w][lane] = ph2;
    __syncthreads();
    float mxn2b = pB[0][0][lane] + pB[0][1][lane] + pB[0][2][lane] + pB[0][3][lane];
    float mxhb2 = pB[1][0][lane] + pB[1][1][lane] + pB[1][2][lane] + pB[1][3][lane];
    {
        float xn = fmaxf(z2n, EPS);
        float mxn = fmaxf(sqrtf(mxn2b), EPS);
        float t = fminf(SQRT_C * xn, 1.0f - 1e-7f);
        float th = tanhf(mxn / xn * atanhf(t));
        float rs = th / (mxn * SQRT_C);
        float rn = th / SQRT_C;
        if (mxn2b == 0.0f) { rs = 0.f; rn = 0.f; }
        if (rn > MAXNORM) { rs *= MAXNORM / rn; rn = MAXNORM; }
        float xy = rs * mxhb2;
        float x2 = rn * rn;
        float A = 1.0f + 2.0f * CC * xy + CC * y2b;
        float B = 1.0f - CC * x2;
        float rden = 1.0f / fmaxf(1.0f + 2.0f * CC * xy + CC * CC * x2 * y2b, EPS);
        float pz = 0.f;
#pragma unroll
        for (int oj = 0; oj < 16; ++oj) {
            float z = (A * rs * a2[oj] + B * hb2f[ob + oj]) * rden;
            a2[oj] = z;
            pz = fmaf(z, z, pz);
        }
        // R5 (buf A): reduce final zn2
        pA[0][w][lane] = pz;
        __syncthreads();
        float zn2 = pA[0][0][lane] + pA[0][1][lane] + pA[0][2][lane] + pA[0][3][lane];
        float zn = fmaxf(sqrtf(zn2), EPS);
        float s4 = (zn > MAXNORM) ? MAXNORM / zn : 1.0f;
        // write scaled z4 into transpose tile T[o*65 + node]
#pragma unroll
        for (int oj = 0; oj < 16; ++oj) Z[(ob + oj) * 65 + lane] = a2[oj] * s4;
    }
    __syncthreads();

    // output: wave w stores nodes [w*16, w*16+16), lanes = channels (coalesced)
#pragma unroll 1
    for (int k = 0; k < 16; ++k) {
        int nl = w * 16 + k;
        int ng = base + nl;
        if (ng >= 2 * N_NODES) break;
        float val = Z[lane * 65 + nl];
        if (isbf) ((__hip_bfloat16*)outv)[ng * 64 + lane] = __float2bfloat16(val);
        else      ((float*)outv)[ng * 64 + lane] = val;
    }
}

extern "C" void kernel_launch(void* const* d_in, const int* in_sizes, int n_in,
                              void* d_out, int out_size, void* d_ws, size_t ws_size,
                              hipStream_t stream) {
    // setup_inputs order: history_graphs(0, unused), edge_index(1), emb(2),
    //                     att_i(3), att_j(4), w1(5), b1(6), w2(7), b2(8)
    const int* ei = (const int*)d_in[1];
    const void* emb   = d_in[2];
    const void* att_i = d_in[3];
    const void* att_j = d_in[4];
    const void* w1 = d_in[5];
    const void* b1 = d_in[6];
    const void* w2 = d_in[7];
    const void* b2 = d_in[8];

    // workspace layout (float words), ~5.07 MB total
    float* ws = (float*)d_ws;
    float* xt    = ws;                                // [10000][64]
    float* ai    = ws + 640000;                       // [10000][4]
    float* aj    = ws + 680000;                       // [10000][4]
    float* sup_t = ws + 720000;                       // [16][20000] transposed
    int* cnt   = (int*)(ws + 1040000);                // [2][10000]
    int* off   = (int*)(ws + 1060000);                // [2][10000]
    int* cur   = (int*)(ws + 1080000);                // [2][10000]
    unsigned short* bucket = (unsigned short*)(ws + 1100000);  // [320000] u16
    int* flag  = (int*)(ws + 1260000);                // dtype flag
    float* wf1t = ws + 1260064;                       // [16][64] fp32, c-major
    float* wf2t = ws + 1261088;                       // [64][64] fp32, c-major
    float* hb1f = ws + 1265184;                       // [64]
    float* hb2f = ws + 1265248;                       // [64]
    float* hbn2 = ws + 1265312;                       // [2]

    hipLaunchKernelGGL(init_sniff, dim3(79), dim3(256), 0, stream,
                       cnt, (const unsigned*)emb, flag);
    hipLaunchKernelGGL(pre_count, dim3(3751), dim3(256), 0, stream,
                       emb, att_i, att_j, w1, b1, w2, b2, flag, ei,
                       xt, ai, aj, cnt, wf1t, wf2t, hb1f, hb2f, hbn2);
    hipLaunchKernelGGL(scan_offsets, dim3(1), dim3(1024), 0, stream, cnt, off, cur);
    hipLaunchKernelGGL(edge_scatter, dim3(1250), dim3(256), 0, stream, ei, cur, bucket);
    hipLaunchKernelGGL(node_agg, dim3(5000), dim3(256), 0, stream,
                       off, cur, bucket, ai, aj, xt, sup_t);
    hipLaunchKernelGGL(final_stage, dim3(313), dim3(256), 0, stream,
                       sup_t, wf1t, wf2t, hb1f, hb2f, hbn2, flag, d_out);
}

// Round 7
// 155.380 us; speedup vs baseline: 3.8390x; 1.2094x over previous
//
#include <hip/hip_runtime.h>
#include <hip/hip_bf16.h>

#define N_NODES 10000
#define NE 160000
#define CAP 96              // direct bucket capacity per (slot,node)
#define SQRT_C 0.1f
#define CC 0.01f
#define EPS 1e-15f
#define MAXNORM ((1.0f - 4e-3f) / SQRT_C)   // geoopt projx boundary, 9.96

// dual-dtype load: harness may hand float arrays as bf16 or float32; a sniffer
// kernel votes once and every load branches (wave-uniform) on the flag.
__device__ __forceinline__ float ldf(const void* p, int i, int isbf) {
    return isbf ? __bfloat162float(((const __hip_bfloat16*)p)[i])
                : ((const float*)p)[i];
}

// ---------- wave-wide helpers (wave64) ----------
__device__ __forceinline__ float wsum(float v) {
#pragma unroll
    for (int off = 32; off > 0; off >>= 1) v += __shfl_xor(v, off, 64);
    return v;
}
__device__ __forceinline__ float wmax(float v) {
#pragma unroll
    for (int off = 32; off > 0; off >>= 1) v = fmaxf(v, __shfl_xor(v, off, 64));
    return v;
}

// ---------- kernel 0: zero per-node counters + overflow cursor + sniff dtype ----------
__global__ __launch_bounds__(256) void init_sniff(int* __restrict__ cnt,
                                                  int* __restrict__ ovf_cnt,
                                                  const unsigned* __restrict__ embw,
                                                  int* __restrict__ flag) {
    int t = blockIdx.x * 256 + threadIdx.x;
    if (t < 2 * N_NODES) cnt[t] = 0;
    if (t == 0) *ovf_cnt = 0;
    if (blockIdx.x == 0 && threadIdx.x < 64) {   // one full wave
        unsigned w = embw[threadIdx.x];
        unsigned e = (w >> 7) & 0xFFu;           // exponent of low-half bf16
        unsigned long long m = __ballot(e >= 116u && e <= 133u);
        if (threadIdx.x == 0) *flag = (__popcll(m) >= 32) ? 1 : 0;
    }
}

// only graphs 3 (b=0) and 7 (b=1) reach the output (last-timestep slice)
#define EDGE_PREAMBLE(T)                                                  \
    int slot = ((T) >= NE) ? 1 : 0;                                       \
    int e = (T) - slot * NE;                                              \
    int g = slot ? 7 : 3;

// ---------- kernel 1: fused node features + direct-bucket scatter + weights ----------
// blocks [0,2500): wave-per-node tangent features + attention dots
// blocks [2500,3750): scatter dst into fixed-capacity buckets (no scan needed)
// block 3750: convert weights to fp32 TRANSPOSED (c-major) + hyperbolic biases
__global__ __launch_bounds__(256) void pre_scatter(const void* __restrict__ emb,
                                                   const void* __restrict__ att_i,
                                                   const void* __restrict__ att_j,
                                                   const void* __restrict__ w1g,
                                                   const void* __restrict__ b1g,
                                                   const void* __restrict__ w2g,
                                                   const void* __restrict__ b2g,
                                                   const int* __restrict__ flag,
                                                   const int* __restrict__ ei,
                                                   float* __restrict__ xt,
                                                   float* __restrict__ ai,
                                                   float* __restrict__ aj,
                                                   int* __restrict__ cnt,
                                                   unsigned short* __restrict__ bucket,
                                                   int* __restrict__ ovf_cnt,
                                                   unsigned* __restrict__ ovf,
                                                   float* __restrict__ wf1t,
                                                   float* __restrict__ wf2t,
                                                   float* __restrict__ hb1f,
                                                   float* __restrict__ hb2f,
                                                   float* __restrict__ hbn2) {
    if (blockIdx.x < 2500) {
        int isbf = *flag;
        int t = blockIdx.x * 256 + threadIdx.x;   // 10000*64 threads exact
        int node = t >> 6;
        int lane = t & 63;
        float u = ldf(emb, node * 64 + lane, isbf);
        // xt = logmap0(projx(expmap0(u))): one wsum, then analytic norms
        float n = fmaxf(sqrtf(wsum(u * u)), EPS);
        float th = tanhf(SQRT_C * n);
        float x0 = th / (SQRT_C * n) * u;
        float x0n = th / SQRT_C;
        if (x0n > MAXNORM) { x0 *= MAXNORM / x0n; x0n = MAXNORM; }
        float tc = fminf(SQRT_C * x0n, 1.0f - 1e-7f);
        float xv = atanhf(tc) / (SQRT_C * x0n) * x0;
        xt[node * 64 + lane] = xv;
        float pi = xv * ldf(att_i, lane, isbf);
        float pj = xv * ldf(att_j, lane, isbf);
#pragma unroll
        for (int off = 8; off > 0; off >>= 1) {   // aligned 16-lane head groups
            pi += __shfl_xor(pi, off, 64);
            pj += __shfl_xor(pj, off, 64);
        }
        if ((lane & 15) == 0) {
            ai[node * 4 + (lane >> 4)] = pi;
            aj[node * 4 + (lane >> 4)] = pj;
        }
    } else if (blockIdx.x < 3750) {
        int t = (blockIdx.x - 2500) * 256 + threadIdx.x;   // 2*NE exact
        EDGE_PREAMBLE(t);
        int src = ei[g * 2 * NE + e];
        int dst = ei[g * 2 * NE + NE + e];
        int i = slot * N_NODES + src;
        int pos = atomicAdd(&cnt[i], 1);
        if (pos < CAP) bucket[i * CAP + pos] = (unsigned short)dst;
        else {
            int oi = atomicAdd(ovf_cnt, 1);      // astronomically rare (deg>96)
            ovf[oi] = ((unsigned)slot << 28) | ((unsigned)src << 14) | (unsigned)dst;
        }
    } else {
        int isbf = *flag;
        int tid = threadIdx.x;
        for (int i = tid; i < 1024; i += 256) {            // w1[o][c] -> wf1t[c*64+o]
            int o = i >> 4, c = i & 15;
            wf1t[c * 64 + o] = ldf(w1g, i, isbf);
        }
        for (int i = tid; i < 4096; i += 256) {            // w2[o][c] -> wf2t[c*64+o]
            int o = i >> 6, c = i & 63;
            wf2t[c * 64 + o] = ldf(w2g, i, isbf);
        }
        int w = tid >> 6, lane = tid & 63;
        if (w < 2) {                               // hb = projx(expmap0(b)), + norm^2
            const void* bg = w ? b2g : b1g;
            float b = ldf(bg, lane, isbf);
            float n = fmaxf(sqrtf(wsum(b * b)), EPS);
            float th = tanhf(SQRT_C * n);
            float hv = th / (SQRT_C * n) * b;
            float hn = th / SQRT_C;
            if (hn > MAXNORM) { hv *= MAXNORM / hn; hn = MAXNORM; }
            (w ? hb2f : hb1f)[lane] = hv;
            if (lane == 0) hbn2[w] = hn * hn;
        }
    }
}

// ---------- kernel 2: per-node softmax + aggregation, atomic-free ----------
// fast path (deg<=63): edge-per-lane softmax (1 exp per edge), weights staged
// in LDS, gather loop unrolled x4 (4 loads in flight). Self-loop = lane cnt.
__global__ __launch_bounds__(256) void node_agg(const int* __restrict__ cnt,
                                                const unsigned short* __restrict__ bucket,
                                                const int* __restrict__ ovf_cnt,
                                                const unsigned* __restrict__ ovf,
                                                const float* __restrict__ ai,
                                                const float* __restrict__ aj,
                                                const float* __restrict__ xt,
                                                float* __restrict__ sup_t) {
    __shared__ float wlds[4][64 * 4];
    __shared__ int dlds[4][64];
    int w = threadIdx.x >> 6, lane = threadIdx.x & 63;
    int idx = blockIdx.x * 4 + w;          // grid exact: 20000 waves
    int slot = (idx >= N_NODES) ? 1 : 0;
    int n = idx - slot * N_NODES;
    int deg = cnt[idx];
    int start = idx * CAP;

    float4 ai4 = *(const float4*)&ai[n * 4];
    float4 aj4n = *(const float4*)&aj[n * 4];
    float ain[4] = {ai4.x, ai4.y, ai4.z, ai4.w};
    float ajn[4] = {aj4n.x, aj4n.y, aj4n.z, aj4n.w};
    int hh = lane >> 4;
    float acc;

    if (deg <= 63) {
        bool act = (lane <= deg);                  // lane==deg is the self-loop
        int d = (lane < deg) ? (int)bucket[start + lane] : n;
        float4 a4 = act ? *(const float4*)&aj[d * 4] : make_float4(0.f, 0.f, 0.f, 0.f);
        float ajv[4] = {a4.x, a4.y, a4.z, a4.w};
        float al[4], mh[4], eh[4];
#pragma unroll
        for (int h = 0; h < 4; ++h) {
            float a = ain[h] + ajv[h];
            a = (a < 0.0f) ? 0.2f * a : a;
            al[h] = act ? a : -1e30f;
            mh[h] = al[h];
        }
#pragma unroll
        for (int h = 0; h < 4; ++h) mh[h] = wmax(mh[h]);
#pragma unroll
        for (int h = 0; h < 4; ++h) eh[h] = act ? expf(al[h] - mh[h]) : 0.0f;
        float sh[4];
#pragma unroll
        for (int h = 0; h < 4; ++h) sh[h] = wsum(eh[h]);
#pragma unroll
        for (int h = 0; h < 4; ++h)
            wlds[w][lane * 4 + h] = eh[h] * (0.25f / (sh[h] + 1e-16f));
        dlds[w][lane] = d;
        // gather, unrolled x4 with independent accumulators (4 loads in flight)
        int m = deg + 1;
        float a0 = 0.f, a1 = 0.f, a2 = 0.f, a3 = 0.f;
        int e = 0;
        for (; e + 4 <= m; e += 4) {
            int d0 = dlds[w][e], d1 = dlds[w][e + 1];
            int d2 = dlds[w][e + 2], d3 = dlds[w][e + 3];
            float w0 = wlds[w][(e + 0) * 4 + hh], w1 = wlds[w][(e + 1) * 4 + hh];
            float w2 = wlds[w][(e + 2) * 4 + hh], w3 = wlds[w][(e + 3) * 4 + hh];
            a0 = fmaf(w0, xt[d0 * 64 + lane], a0);
            a1 = fmaf(w1, xt[d1 * 64 + lane], a1);
            a2 = fmaf(w2, xt[d2 * 64 + lane], a2);
            a3 = fmaf(w3, xt[d3 * 64 + lane], a3);
        }
        for (; e < m; ++e)
            a0 = fmaf(wlds[w][e * 4 + hh], xt[dlds[w][e] * 64 + lane], a0);
        acc = (a0 + a1) + (a2 + a3);
    } else {
        // slow path: strided over bucket (first min(deg,CAP)) + overflow scan
        int bdeg = (deg < CAP) ? deg : CAP;
        int tov = (deg > CAP) ? *ovf_cnt : 0;
        float mh[4];
#pragma unroll
        for (int h = 0; h < 4; ++h) {
            float a = ain[h] + ajn[h];
            mh[h] = (a < 0.0f) ? 0.2f * a : a;
        }
        for (int e = lane; e < bdeg; e += 64) {
            int d = bucket[start + e];
#pragma unroll
            for (int h = 0; h < 4; ++h) {
                float a = ain[h] + aj[d * 4 + h];
                a = (a < 0.0f) ? 0.2f * a : a;
                mh[h] = fmaxf(mh[h], a);
            }
        }
        for (int k = lane; k < tov; k += 64) {
            unsigned pe = ovf[k];
            if ((int)(pe >> 28) == slot && (int)((pe >> 14) & 0x3FFFu) == n) {
                int d = pe & 0x3FFFu;
#pragma unroll
                for (int h = 0; h < 4; ++h) {
                    float a = ain[h] + aj[d * 4 + h];
                    a = (a < 0.0f) ? 0.2f * a : a;
                    mh[h] = fmaxf(mh[h], a);
                }
            }
        }
#pragma unroll
        for (int h = 0; h < 4; ++h) mh[h] = wmax(mh[h]);
        float sh[4] = {0.f, 0.f, 0.f, 0.f};
        if (lane == 0) {
#pragma unroll
            for (int h = 0; h < 4; ++h) {
                float a = ain[h] + ajn[h];
                a = (a < 0.0f) ? 0.2f * a : a;
                sh[h] = expf(a - mh[h]);
            }
        }
        for (int e = lane; e < bdeg; e += 64) {
            int d = bucket[start + e];
#pragma unroll
            for (int h = 0; h < 4; ++h) {
                float a = ain[h] + aj[d * 4 + h];
                a = (a < 0.0f) ? 0.2f * a : a;
                sh[h] += expf(a - mh[h]);
            }
        }
        for (int k = lane; k < tov; k += 64) {
            unsigned pe = ovf[k];
            if ((int)(pe >> 28) == slot && (int)((pe >> 14) & 0x3FFFu) == n) {
                int d = pe & 0x3FFFu;
#pragma unroll
                for (int h = 0; h < 4; ++h) {
                    float a = ain[h] + aj[d * 4 + h];
                    a = (a < 0.0f) ? 0.2f * a : a;
                    sh[h] += expf(a - mh[h]);
                }
            }
        }
#pragma unroll
        for (int h = 0; h < 4; ++h) sh[h] = wsum(sh[h]);
        float scale[4];
#pragma unroll
        for (int h = 0; h < 4; ++h) scale[h] = 0.25f / (sh[h] + 1e-16f);
        float aih = ain[hh], mhh = mh[hh], sch = scale[hh];
        float aself = aih + ajn[hh];
        aself = (aself < 0.0f) ? 0.2f * aself : aself;
        acc = expf(aself - mhh) * sch * xt[n * 64 + lane];
        for (int e = 0; e < bdeg; ++e) {
            int d = bucket[start + e];
            float a = aih + aj[d * 4 + hh];
            a = (a < 0.0f) ? 0.2f * a : a;
            acc = fmaf(expf(a - mhh) * sch, xt[d * 64 + lane], acc);
        }
        for (int k = 0; k < tov; ++k) {
            unsigned pe = ovf[k];
            if ((int)(pe >> 28) == slot && (int)((pe >> 14) & 0x3FFFu) == n) {
                int d = pe & 0x3FFFu;
                float a = aih + aj[d * 4 + hh];
                a = (a < 0.0f) ? 0.2f * a : a;
                acc = fmaf(expf(a - mhh) * sch, xt[d * 64 + lane], acc);
            }
        }
    }
    acc += __shfl_xor(acc, 16, 64);        // head mean (x0.25 in scale)
    acc += __shfl_xor(acc, 32, 64);
    if (lane < 16) sup_t[lane * 20000 + idx] = acc;
}

// ---------- kernel 3: hyperbolic head, 4-wave cooperative ----------
__global__ __launch_bounds__(256) void final_stage(const float* __restrict__ sup_t,
                                                   const float* __restrict__ wf1t,
                                                   const float* __restrict__ wf2t,
                                                   const float* __restrict__ hb1f,
                                                   const float* __restrict__ hb2f,
                                                   const float* __restrict__ hbn2,
                                                   const int* __restrict__ flag,
                                                   void* __restrict__ outv) {
    __shared__ float Z[65 * 64];           // z2s [c*64+node] then T [o*65+node]
    __shared__ float pA[2][4][64];
    __shared__ float pB[2][4][64];
    int w = threadIdx.x >> 6, lane = threadIdx.x & 63;
    int base = blockIdx.x * 64;            // grid: 313 blocks
    int nd = base + lane;
    bool valid = (nd < 2 * N_NODES);
    int isbf = *flag;
    float y2a = hbn2[0], y2b = hbn2[1];
    int ob = w * 16;                       // owned output base

    float v[16];
#pragma unroll
    for (int c = 0; c < 16; ++c) v[c] = valid ? sup_t[c * 20000 + nd] : 0.0f;
    float n2 = 0.f;
#pragma unroll
    for (int c = 0; c < 16; ++c) n2 = fmaf(v[c], v[c], n2);
    float n = fmaxf(sqrtf(n2), EPS);
    float th0 = tanhf(SQRT_C * n);
    float s0 = th0 / (SQRT_C * n);
    float x0n = th0 / SQRT_C;
    if (x0n > MAXNORM) { s0 *= MAXNORM / x0n; x0n = MAXNORM; }
#pragma unroll
    for (int c = 0; c < 16; ++c) v[c] *= s0;

    float a1[16];
#pragma unroll
    for (int oj = 0; oj < 16; ++oj) a1[oj] = 0.f;
#pragma unroll
    for (int c = 0; c < 16; ++c) {
        float vc = v[c];
#pragma unroll
        for (int oj = 0; oj < 16; ++oj)
            a1[oj] = fmaf(wf1t[c * 64 + ob + oj], vc, a1[oj]);
    }
    float pn = 0.f, ph = 0.f;
#pragma unroll
    for (int oj = 0; oj < 16; ++oj) {
        pn = fmaf(a1[oj], a1[oj], pn);
        ph = fmaf(a1[oj], hb1f[ob + oj], ph);
    }
    pA[0][w][lane] = pn; pA[1][w][lane] = ph;
    __syncthreads();
    float mxn2 = pA[0][0][lane] + pA[0][1][lane] + pA[0][2][lane] + pA[0][3][lane];
    float mxhb = pA[1][0][lane] + pA[1][1][lane] + pA[1][2][lane] + pA[1][3][lane];

    float z2n;
    {
        float xn = fmaxf(x0n, EPS);
        float mxn = fmaxf(sqrtf(mxn2), EPS);
        float t = fminf(SQRT_C * xn, 1.0f - 1e-7f);
        float th = tanhf(mxn / xn * atanhf(t));
        float rs = th / (mxn * SQRT_C);
        float rn = th / SQRT_C;
        if (mxn2 == 0.0f) { rs = 0.f; rn = 0.f; }
        if (rn > MAXNORM) { rs *= MAXNORM / rn; rn = MAXNORM; }
        float xy = rs * mxhb;
        float x2 = rn * rn;
        float A = 1.0f + 2.0f * CC * xy + CC * y2a;
        float B = 1.0f - CC * x2;
        float rden = 1.0f / fmaxf(1.0f + 2.0f * CC * xy + CC * CC * x2 * y2a, EPS);
        float pz = 0.f;
#pragma unroll
        for (int oj = 0; oj < 16; ++oj) {
            float z = (A * rs * a1[oj] + B * hb1f[ob + oj]) * rden;
            a1[oj] = z;
            pz = fmaf(z, z, pz);
        }
        pB[0][w][lane] = pz;
        __syncthreads();
        float zn2 = pB[0][0][lane] + pB[0][1][lane] + pB[0][2][lane] + pB[0][3][lane];
        float zn = fmaxf(sqrtf(zn2), EPS);
        float sc = (zn > MAXNORM) ? MAXNORM / zn : 1.0f;
        float z1n = fminf(zn, MAXNORM);
        float lg = atanhf(fminf(SQRT_C * z1n, 1.0f - 1e-7f)) / (SQRT_C * z1n) * sc;
        float pu = 0.f;
#pragma unroll
        for (int oj = 0; oj < 16; ++oj) {
            float u = lg * a1[oj];
            u = u / (1.0f + expf(-u));
            a1[oj] = u;
            pu = fmaf(u, u, pu);
        }
        pA[0][w][lane] = pu;
        __syncthreads();
        float un2 = pA[0][0][lane] + pA[0][1][lane] + pA[0][2][lane] + pA[0][3][lane];
        float un = fmaxf(sqrtf(un2), EPS);
        float th2 = tanhf(SQRT_C * un);
        float s2 = th2 / (SQRT_C * un);
        z2n = th2 / SQRT_C;
        if (z2n > MAXNORM) { s2 *= MAXNORM / z2n; z2n = MAXNORM; }
#pragma unroll
        for (int oj = 0; oj < 16; ++oj) Z[(ob + oj) * 64 + lane] = a1[oj] * s2;
        // HypDropout eval round-trip == identity (no clip possible) -> skip
    }
    __syncthreads();

    float a2[16];
#pragma unroll
    for (int oj = 0; oj < 16; ++oj) a2[oj] = 0.f;
#pragma unroll 4
    for (int c = 0; c < 64; ++c) {
        float zc = Z[c * 64 + lane];
#pragma unroll
        for (int oj = 0; oj < 16; ++oj)
            a2[oj] = fmaf(wf2t[c * 64 + ob + oj], zc, a2[oj]);
    }
    float pn2 = 0.f, ph2 = 0.f;
#pragma unroll
    for (int oj = 0; oj < 16; ++oj) {
        pn2 = fmaf(a2[oj], a2[oj], pn2);
        ph2 = fmaf(a2[oj], hb2f[ob + oj], ph2);
    }
    pB[0][w][lane] = pn2; pB[1][w][lane] = ph2;
    __syncthreads();
    float mxn2b = pB[0][0][lane] + pB[0][1][lane] + pB[0][2][lane] + pB[0][3][lane];
    float mxhb2 = pB[1][0][lane] + pB[1][1][lane] + pB[1][2][lane] + pB[1][3][lane];
    {
        float xn = fmaxf(z2n, EPS);
        float mxn = fmaxf(sqrtf(mxn2b), EPS);
        float t = fminf(SQRT_C * xn, 1.0f - 1e-7f);
        float th = tanhf(mxn / xn * atanhf(t));
        float rs = th / (mxn * SQRT_C);
        float rn = th / SQRT_C;
        if (mxn2b == 0.0f) { rs = 0.f; rn = 0.f; }
        if (rn > MAXNORM) { rs *= MAXNORM / rn; rn = MAXNORM; }
        float xy = rs * mxhb2;
        float x2 = rn * rn;
        float A = 1.0f + 2.0f * CC * xy + CC * y2b;
        float B = 1.0f - CC * x2;
        float rden = 1.0f / fmaxf(1.0f + 2.0f * CC * xy + CC * CC * x2 * y2b, EPS);
        float pz = 0.f;
#pragma unroll
        for (int oj = 0; oj < 16; ++oj) {
            float z = (A * rs * a2[oj] + B * hb2f[ob + oj]) * rden;
            a2[oj] = z;
            pz = fmaf(z, z, pz);
        }
        pA[0][w][lane] = pz;
        __syncthreads();
        float zn2 = pA[0][0][lane] + pA[0][1][lane] + pA[0][2][lane] + pA[0][3][lane];
        float zn = fmaxf(sqrtf(zn2), EPS);
        float s4 = (zn > MAXNORM) ? MAXNORM / zn : 1.0f;
#pragma unroll
        for (int oj = 0; oj < 16; ++oj) Z[(ob + oj) * 65 + lane] = a2[oj] * s4;
    }
    __syncthreads();

#pragma unroll 1
    for (int k = 0; k < 16; ++k) {
        int nl = w * 16 + k;
        int ng = base + nl;
        if (ng >= 2 * N_NODES) break;
        float val = Z[lane * 65 + nl];
        if (isbf) ((__hip_bfloat16*)outv)[ng * 64 + lane] = __float2bfloat16(val);
        else      ((float*)outv)[ng * 64 + lane] = val;
    }
}

extern "C" void kernel_launch(void* const* d_in, const int* in_sizes, int n_in,
                              void* d_out, int out_size, void* d_ws, size_t ws_size,
                              hipStream_t stream) {
    // setup_inputs order: history_graphs(0, unused), edge_index(1), emb(2),
    //                     att_i(3), att_j(4), w1(5), b1(6), w2(7), b2(8)
    const int* ei = (const int*)d_in[1];
    const void* emb   = d_in[2];
    const void* att_i = d_in[3];
    const void* att_j = d_in[4];
    const void* w1 = d_in[5];
    const void* b1 = d_in[6];
    const void* w2 = d_in[7];
    const void* b2 = d_in[8];

    // workspace layout (float words), ~9.4 MB total
    float* ws = (float*)d_ws;
    float* xt    = ws;                                // [10000][64]
    float* ai    = ws + 640000;                       // [10000][4]
    float* aj    = ws + 680000;                       // [10000][4]
    float* sup_t = ws + 720000;                       // [16][20000] transposed
    int* cnt   = (int*)(ws + 1040000);                // [2][10000]
    unsigned short* bucket = (unsigned short*)(ws + 1060000);  // [20000][96] u16
    unsigned* ovf = (unsigned*)(ws + 2020000);        // [320000] packed overflow
    int* ovf_cnt  = (int*)(ws + 2340000);
    int* flag     = (int*)(ws + 2340001);
    float* wf1t = ws + 2340032;                       // [16][64] fp32, c-major
    float* wf2t = ws + 2341056;                       // [64][64] fp32, c-major
    float* hb1f = ws + 2345152;                       // [64]
    float* hb2f = ws + 2345216;                       // [64]
    float* hbn2 = ws + 2345280;                       // [2]

    hipLaunchKernelGGL(init_sniff, dim3(79), dim3(256), 0, stream,
                       cnt, ovf_cnt, (const unsigned*)emb, flag);
    hipLaunchKernelGGL(pre_scatter, dim3(3751), dim3(256), 0, stream,
                       emb, att_i, att_j, w1, b1, w2, b2, flag, ei,
                       xt, ai, aj, cnt, bucket, ovf_cnt, ovf,
                       wf1t, wf2t, hb1f, hb2f, hbn2);
    hipLaunchKernelGGL(node_agg, dim3(5000), dim3(256), 0, stream,
                       cnt, bucket, ovf_cnt, ovf, ai, aj, xt, sup_t);
    hipLaunchKernelGGL(final_stage, dim3(313), dim3(256), 0, stream,
                       sup_t, wf1t, wf2t, hb1f, hb2f, hbn2, flag, d_out);
}